// Round 1
// baseline (3619.885 us; speedup 1.0000x reference)
//
#include <hip/hip_runtime.h>
#include <math.h>

#define N_NODES 20000
#define N_EDGES 100000
#define N_GRAPHS 64
#define IN_F 63
#define NHEAD 8
#define F 1024            // NHEAD * HID
#define NCLS 18
#define BN_EPS 1e-5f
#define BN_CHUNKS 128

// ---------------- utility kernels ----------------
__global__ void k_zero_i32(int* __restrict__ p, int n) {
    int i = blockIdx.x * blockDim.x + threadIdx.x;
    if (i < n) p[i] = 0;
}

__global__ void k_copy_i32(int* __restrict__ d, const int* __restrict__ s, int n) {
    int i = blockIdx.x * blockDim.x + threadIdx.x;
    if (i < n) d[i] = s[i];
}

// ---------------- CSR build over dst ----------------
__global__ void k_count(const int* __restrict__ dst, int* __restrict__ cnt) {
    int i = blockIdx.x * blockDim.x + threadIdx.x;
    if (i < N_EDGES) atomicAdd(&cnt[dst[i]], 1);
}

__global__ void k_scan(const int* __restrict__ cnt, int* __restrict__ off) {
    // single block, 256 threads; exclusive scan over N_NODES counts
    __shared__ int tsum[256];
    const int CH = (N_NODES + 255) / 256;
    int t = threadIdx.x;
    int s = 0;
    for (int i = 0; i < CH; ++i) {
        int idx = t * CH + i;
        if (idx < N_NODES) s += cnt[idx];
    }
    tsum[t] = s;
    __syncthreads();
    if (t == 0) {
        int acc = 0;
        for (int i = 0; i < 256; ++i) { int v = tsum[i]; tsum[i] = acc; acc += v; }
    }
    __syncthreads();
    int run = tsum[t];
    for (int i = 0; i < CH; ++i) {
        int idx = t * CH + i;
        if (idx < N_NODES) { off[idx] = run; run += cnt[idx]; }
    }
    if (t == 255) off[N_NODES] = run;
}

__global__ void k_fill(const int* __restrict__ dst, int* __restrict__ cursor,
                       int* __restrict__ csr_e) {
    int i = blockIdx.x * blockDim.x + threadIdx.x;
    if (i < N_EDGES) {
        int p = atomicAdd(&cursor[dst[i]], 1);
        csr_e[p] = i;
    }
}

__global__ void k_sort_buckets(const int* __restrict__ off, int* __restrict__ csr_e) {
    int n = blockIdx.x * blockDim.x + threadIdx.x;
    if (n >= N_NODES) return;
    int b = off[n], e = off[n + 1];
    for (int i = b + 1; i < e; ++i) {
        int v = csr_e[i];
        int j = i - 1;
        while (j >= b && csr_e[j] > v) { csr_e[j + 1] = csr_e[j]; --j; }
        csr_e[j + 1] = v;
    }
}

__global__ void k_gstart(const int* __restrict__ gid, int* __restrict__ gstart) {
    int g = blockIdx.x * blockDim.x + threadIdx.x;
    if (g > N_GRAPHS) return;
    int lo = 0, hi = N_NODES;
    while (lo < hi) {
        int mid = (lo + hi) >> 1;
        if (gid[mid] < g) lo = mid + 1; else hi = mid;
    }
    gstart[g] = lo;
}

// ---------------- f32 tiled GEMM: C = A(MxK) @ W(KxN) + bias ----------------
#define BMT 64
#define BNT 64
#define BKT 16
__launch_bounds__(256)
__global__ void k_gemm(const float* __restrict__ A, const float* __restrict__ W,
                       const float* __restrict__ bias, float* __restrict__ C,
                       int M, int K, int Nout) {
    __shared__ float As[BKT][BMT + 4];
    __shared__ float Ws[BKT][BNT + 4];
    int tid = threadIdx.x;
    int rb = blockIdx.y * BMT;
    int cb = blockIdx.x * BNT;
    int tx = tid & 15, ty = tid >> 4;
    float acc[4][4] = {};

    int la_r = tid >> 2;           // 0..63
    int la_k = (tid & 3) * 4;      // 0,4,8,12
    int lw_k = tid >> 4;           // 0..15
    int lw_c = (tid & 15) * 4;     // 0..60
    bool k4 = (K % 4 == 0);

    for (int k0 = 0; k0 < K; k0 += BKT) {
        // A tile
        {
            int row = rb + la_r;
            float v0 = 0.f, v1 = 0.f, v2 = 0.f, v3 = 0.f;
            if (row < M) {
                const float* p = A + (size_t)row * K + k0 + la_k;
                if (k4 && (k0 + la_k + 3 < K)) {
                    float4 t4 = *(const float4*)p;
                    v0 = t4.x; v1 = t4.y; v2 = t4.z; v3 = t4.w;
                } else {
                    if (k0 + la_k + 0 < K) v0 = p[0];
                    if (k0 + la_k + 1 < K) v1 = p[1];
                    if (k0 + la_k + 2 < K) v2 = p[2];
                    if (k0 + la_k + 3 < K) v3 = p[3];
                }
            }
            As[la_k + 0][la_r] = v0;
            As[la_k + 1][la_r] = v1;
            As[la_k + 2][la_r] = v2;
            As[la_k + 3][la_r] = v3;
        }
        // W tile
        {
            int krow = k0 + lw_k;
            float4 t4 = {0.f, 0.f, 0.f, 0.f};
            if (krow < K) t4 = *(const float4*)(W + (size_t)krow * Nout + cb + lw_c);
            Ws[lw_k][lw_c + 0] = t4.x;
            Ws[lw_k][lw_c + 1] = t4.y;
            Ws[lw_k][lw_c + 2] = t4.z;
            Ws[lw_k][lw_c + 3] = t4.w;
        }
        __syncthreads();
#pragma unroll
        for (int kk = 0; kk < BKT; ++kk) {
            float a0 = As[kk][ty * 4 + 0], a1 = As[kk][ty * 4 + 1];
            float a2 = As[kk][ty * 4 + 2], a3 = As[kk][ty * 4 + 3];
            float b0 = Ws[kk][tx * 4 + 0], b1 = Ws[kk][tx * 4 + 1];
            float b2 = Ws[kk][tx * 4 + 2], b3 = Ws[kk][tx * 4 + 3];
            acc[0][0] += a0 * b0; acc[0][1] += a0 * b1; acc[0][2] += a0 * b2; acc[0][3] += a0 * b3;
            acc[1][0] += a1 * b0; acc[1][1] += a1 * b1; acc[1][2] += a1 * b2; acc[1][3] += a1 * b3;
            acc[2][0] += a2 * b0; acc[2][1] += a2 * b1; acc[2][2] += a2 * b2; acc[2][3] += a2 * b3;
            acc[3][0] += a3 * b0; acc[3][1] += a3 * b1; acc[3][2] += a3 * b2; acc[3][3] += a3 * b3;
        }
        __syncthreads();
    }
#pragma unroll
    for (int i = 0; i < 4; ++i) {
        int row = rb + ty * 4 + i;
        if (row >= M) continue;
#pragma unroll
        for (int j = 0; j < 4; ++j) {
            int col = cb + tx * 4 + j;
            C[(size_t)row * Nout + col] = acc[i][j] + bias[col];
        }
    }
}

// ---------------- edge scores: sc[e,h] = sum_d attn[h,d]*lrelu02(fs[src]+fd[dst]) ----------------
__launch_bounds__(256)
__global__ void k_edge(const float* __restrict__ fs, const float* __restrict__ fd,
                       const int* __restrict__ src, const int* __restrict__ dst,
                       const float* __restrict__ attn, float* __restrict__ sc) {
    int g = blockIdx.x * blockDim.x + threadIdx.x;
    int e = g >> 6;
    int lane = g & 63;
    if (e >= N_EDGES) return;
    int s = src[e], d = dst[e];
    const float4* ps = (const float4*)(fs + (size_t)s * F) + lane * 4;
    const float4* pd = (const float4*)(fd + (size_t)d * F) + lane * 4;
    const float4* pa = (const float4*)attn + lane * 4;
    float acc = 0.f;
#pragma unroll
    for (int j = 0; j < 4; ++j) {
        float4 a = ps[j], b = pd[j], w = pa[j];
        float v;
        v = a.x + b.x; v = v > 0.f ? v : 0.2f * v; acc += v * w.x;
        v = a.y + b.y; v = v > 0.f ? v : 0.2f * v; acc += v * w.y;
        v = a.z + b.z; v = v > 0.f ? v : 0.2f * v; acc += v * w.z;
        v = a.w + b.w; v = v > 0.f ? v : 0.2f * v; acc += v * w.w;
    }
    acc += __shfl_xor(acc, 1);
    acc += __shfl_xor(acc, 2);
    acc += __shfl_xor(acc, 4);
    if ((lane & 7) == 0) sc[e * NHEAD + (lane >> 3)] = acc;
}

// ---------------- per-node softmax + aggregation (+bias) ----------------
__launch_bounds__(256)
__global__ void k_agg(const float* __restrict__ fs, const float* __restrict__ sc,
                      const int* __restrict__ off, const int* __restrict__ csr_e,
                      const int* __restrict__ src, const float* __restrict__ bias,
                      float* __restrict__ y) {
    int n = blockIdx.x;
    int t = threadIdx.x;
    __shared__ float sm[NHEAD], sinv[NHEAD];
    int b = off[n], e = off[n + 1];
    if (t < NHEAD) {
        float mm = -1e30f;
        for (int i = b; i < e; ++i) mm = fmaxf(mm, sc[csr_e[i] * NHEAD + t]);
        float den = 0.f;
        for (int i = b; i < e; ++i) den += __expf(sc[csr_e[i] * NHEAD + t] - mm);
        sm[t] = mm;
        sinv[t] = (e > b) ? 1.f / den : 0.f;
    }
    __syncthreads();
    int h = t >> 5;           // 256 threads * 4 dims: dims t*4.. -> head = t*4/128
    float mh = sm[h], ih = sinv[h];
    float ax = 0.f, ay = 0.f, az = 0.f, aw = 0.f;
    for (int i = b; i < e; ++i) {
        int ed = csr_e[i];
        float alpha = __expf(sc[ed * NHEAD + h] - mh) * ih;
        float4 v = *(const float4*)(fs + (size_t)src[ed] * F + t * 4);
        ax += alpha * v.x; ay += alpha * v.y; az += alpha * v.z; aw += alpha * v.w;
    }
    const float4 bb = *(const float4*)(bias + t * 4);
    float4 o;
    o.x = ax + bb.x; o.y = ay + bb.y; o.z = az + bb.z; o.w = aw + bb.w;
    *(float4*)(y + (size_t)n * F + t * 4) = o;
}

// ---------------- BatchNorm (2-stage deterministic) + lrelu ----------------
__global__ void k_bnpart(const float* __restrict__ y, float* __restrict__ part) {
    const int ROWS = (N_NODES + BN_CHUNKS - 1) / BN_CHUNKS;
    int blk = blockIdx.x;
    int t = threadIdx.x;
    int r0 = blk * ROWS;
    int r1 = r0 + ROWS; if (r1 > N_NODES) r1 = N_NODES;
    float sx = 0.f, sy = 0.f, sz = 0.f, sw = 0.f;
    float qx = 0.f, qy = 0.f, qz = 0.f, qw = 0.f;
    for (int r = r0; r < r1; ++r) {
        float4 v = *(const float4*)(y + (size_t)r * F + t * 4);
        sx += v.x; sy += v.y; sz += v.z; sw += v.w;
        qx += v.x * v.x; qy += v.y * v.y; qz += v.z * v.z; qw += v.w * v.w;
    }
    float4 s4; s4.x = sx; s4.y = sy; s4.z = sz; s4.w = sw;
    float4 q4; q4.x = qx; q4.y = qy; q4.z = qz; q4.w = qw;
    *(float4*)(part + (size_t)blk * (2 * F) + t * 4) = s4;
    *(float4*)(part + (size_t)blk * (2 * F) + F + t * 4) = q4;
}

__global__ void k_bnfin(const float* __restrict__ part, const float* __restrict__ gamma,
                        const float* __restrict__ beta, float* __restrict__ scale,
                        float* __restrict__ shift) {
    int c = blockIdx.x * blockDim.x + threadIdx.x;
    if (c >= F) return;
    float s = 0.f, q = 0.f;
    for (int b = 0; b < BN_CHUNKS; ++b) {
        s += part[(size_t)b * (2 * F) + c];
        q += part[(size_t)b * (2 * F) + F + c];
    }
    float mu = s / (float)N_NODES;
    float var = q / (float)N_NODES - mu * mu;
    float sc = gamma[c] * rsqrtf(var + BN_EPS);
    scale[c] = sc;
    shift[c] = beta[c] - mu * sc;
}

__global__ void k_bnapply(const float* __restrict__ y, const float* __restrict__ scale,
                          const float* __restrict__ shift, float* __restrict__ x) {
    int i = blockIdx.x * blockDim.x + threadIdx.x;
    if (i >= N_NODES * (F / 4)) return;
    int c4 = (i & (F / 4 - 1)) * 4;
    float4 v = ((const float4*)y)[i];
    float4 o;
    o.x = v.x * scale[c4 + 0] + shift[c4 + 0];
    o.y = v.y * scale[c4 + 1] + shift[c4 + 1];
    o.z = v.z * scale[c4 + 2] + shift[c4 + 2];
    o.w = v.w * scale[c4 + 3] + shift[c4 + 3];
    o.x = o.x > 0.f ? o.x : 0.01f * o.x;
    o.y = o.y > 0.f ? o.y : 0.01f * o.y;
    o.z = o.z > 0.f ? o.z : 0.01f * o.z;
    o.w = o.w > 0.f ? o.w : 0.01f * o.w;
    ((float4*)x)[i] = o;
}

// ---------------- avg pool per graph ----------------
__global__ void k_pool(const float* __restrict__ x, const int* __restrict__ gstart,
                       float* __restrict__ hg) {
    int g = blockIdx.x;
    int t = threadIdx.x;
    int r0 = gstart[g], r1 = gstart[g + 1];
    float sx = 0.f, sy = 0.f, sz = 0.f, sw = 0.f;
    for (int r = r0; r < r1; ++r) {
        float4 v = *(const float4*)(x + (size_t)r * F + t * 4);
        sx += v.x; sy += v.y; sz += v.z; sw += v.w;
    }
    float inv = (r1 > r0) ? 1.f / (float)(r1 - r0) : 0.f;
    float4 o; o.x = sx * inv; o.y = sy * inv; o.z = sz * inv; o.w = sw * inv;
    *(float4*)(hg + (size_t)g * F + t * 4) = o;
}

// ---------------- small MLP GEMM: out[M, Nout] ----------------
__global__ void k_mlp(const float* __restrict__ X, const float* __restrict__ W,
                      const float* __restrict__ b, float* __restrict__ out,
                      int K, int Nout, int act) {
    __shared__ float xs[1024];
    int row = blockIdx.y;
    int col = blockIdx.x * 256 + threadIdx.x;
    for (int k = threadIdx.x; k < K; k += 256) xs[k] = X[(size_t)row * K + k];
    __syncthreads();
    if (col < Nout) {
        float acc = b[col];
        for (int k = 0; k < K; ++k) acc += xs[k] * W[(size_t)k * Nout + col];
        if (act && acc < 0.f) acc *= 0.01f;
        out[(size_t)row * Nout + col] = acc;
    }
}

// ---------------- host orchestration ----------------
extern "C" void kernel_launch(void* const* d_in, const int* in_sizes, int n_in,
                              void* d_out, int out_size, void* d_ws, size_t ws_size,
                              hipStream_t stream) {
    const float* h   = (const float*)d_in[0];
    const int* src   = (const int*)d_in[1];
    const int* dst   = (const int*)d_in[2];
    const int* gid   = (const int*)d_in[3];

    const float* w_src[3], *b_src[3], *w_dst[3], *b_dst[3], *attn[3], *bias[3], *gamma[3], *beta[3];
    for (int l = 0; l < 3; ++l) {
        int base = 4 + l * 8;
        w_src[l] = (const float*)d_in[base + 0];
        b_src[l] = (const float*)d_in[base + 1];
        w_dst[l] = (const float*)d_in[base + 2];
        b_dst[l] = (const float*)d_in[base + 3];
        attn[l]  = (const float*)d_in[base + 4];
        bias[l]  = (const float*)d_in[base + 5];
        gamma[l] = (const float*)d_in[base + 6];
        beta[l]  = (const float*)d_in[base + 7];
    }
    const float* fc1_w = (const float*)d_in[28];
    const float* fc1_b = (const float*)d_in[29];
    const float* fc2_w = (const float*)d_in[30];
    const float* fc2_b = (const float*)d_in[31];
    const float* fc3_w = (const float*)d_in[32];
    const float* fc3_b = (const float*)d_in[33];

    // workspace carve
    char* base = (char*)d_ws;
    size_t o = 0;
    auto carve = [&](size_t bytes) -> char* {
        char* p = base + o;
        o += (bytes + 255) & ~(size_t)255;
        return p;
    };
    float* xbuf = (float*)carve((size_t)N_NODES * F * 4);
    float* fs   = (float*)carve((size_t)N_NODES * F * 4);
    float* fd   = (float*)carve((size_t)N_NODES * F * 4);   // reused as y after edge scores
    float* sc   = (float*)carve((size_t)N_EDGES * NHEAD * 4);
    int* cnt    = (int*)carve((size_t)N_NODES * 4);
    int* off    = (int*)carve((size_t)(N_NODES + 1) * 4);
    int* cursor = (int*)carve((size_t)N_NODES * 4);
    int* csr_e  = (int*)carve((size_t)N_EDGES * 4);
    float* part = (float*)carve((size_t)BN_CHUNKS * 2 * F * 4);
    float* scale = (float*)carve(F * 4);
    float* shift = (float*)carve(F * 4);
    int* gstart = (int*)carve((N_GRAPHS + 1) * 4);
    float* hg   = (float*)carve((size_t)N_GRAPHS * F * 4);
    float* z1   = (float*)carve((size_t)N_GRAPHS * F * 4);
    float* z2   = (float*)carve((size_t)N_GRAPHS * F * 4);
    float* y    = fd;
    (void)ws_size;

    // ---- CSR build (deterministic: buckets sorted by edge id) ----
    k_zero_i32<<<(N_NODES + 255) / 256, 256, 0, stream>>>(cnt, N_NODES);
    k_count<<<(N_EDGES + 255) / 256, 256, 0, stream>>>(dst, cnt);
    k_scan<<<1, 256, 0, stream>>>(cnt, off);
    k_copy_i32<<<(N_NODES + 255) / 256, 256, 0, stream>>>(cursor, off, N_NODES);
    k_fill<<<(N_EDGES + 255) / 256, 256, 0, stream>>>(dst, cursor, csr_e);
    k_sort_buckets<<<(N_NODES + 255) / 256, 256, 0, stream>>>(off, csr_e);
    k_gstart<<<1, 128, 0, stream>>>(gid, gstart);

    // ---- 3 GATv2 + BN + lrelu layers ----
    const float* xin = h;
    int K = IN_F;
    dim3 ggrid(F / BNT, (N_NODES + BMT - 1) / BMT);
    for (int l = 0; l < 3; ++l) {
        k_gemm<<<ggrid, 256, 0, stream>>>(xin, w_src[l], b_src[l], fs, N_NODES, K, F);
        k_gemm<<<ggrid, 256, 0, stream>>>(xin, w_dst[l], b_dst[l], fd, N_NODES, K, F);
        k_edge<<<(N_EDGES * 64 + 255) / 256, 256, 0, stream>>>(fs, fd, src, dst, attn[l], sc);
        k_agg<<<N_NODES, 256, 0, stream>>>(fs, sc, off, csr_e, src, bias[l], y);
        k_bnpart<<<BN_CHUNKS, 256, 0, stream>>>(y, part);
        k_bnfin<<<F / 256, 256, 0, stream>>>(part, gamma[l], beta[l], scale, shift);
        k_bnapply<<<(N_NODES * (F / 4) + 255) / 256, 256, 0, stream>>>(y, scale, shift, xbuf);
        xin = xbuf;
        K = F;
    }

    // ---- pool + MLP head ----
    k_pool<<<N_GRAPHS, 256, 0, stream>>>(xbuf, gstart, hg);
    k_mlp<<<dim3(4, N_GRAPHS), 256, 0, stream>>>(hg, fc1_w, fc1_b, z1, F, F, 1);
    k_mlp<<<dim3(4, N_GRAPHS), 256, 0, stream>>>(z1, fc2_w, fc2_b, z2, F, F, 1);
    k_mlp<<<dim3(1, N_GRAPHS), 256, 0, stream>>>(z2, fc3_w, fc3_b, (float*)d_out, F, NCLS, 0);
}

// Round 2
// 1912.460 us; speedup vs baseline: 1.8928x; 1.8928x over previous
//
#include <hip/hip_runtime.h>
#include <math.h>

#define N_NODES 20000
#define N_PAD   20096            // 157 * 128
#define N_EDGES 100000
#define N_GRAPHS 64
#define IN_F 63
#define NHEAD 8
#define F 1024                   // NHEAD * HID
#define NCLS 18
#define BN_EPS 1e-5f
#define BN_CHUNKS 128

typedef __attribute__((ext_vector_type(8))) short short8v;   // 8 bf16 (4 VGPRs)
typedef __attribute__((ext_vector_type(4))) float f32x4;
typedef __attribute__((ext_vector_type(4))) unsigned short ushort4v;

__device__ __forceinline__ unsigned short bf16_rne(float f) {
    unsigned int u = __float_as_uint(f);
    u += 0x7fff + ((u >> 16) & 1);
    return (unsigned short)(u >> 16);
}
__device__ __forceinline__ float bf16_f32(unsigned short h) {
    return __uint_as_float((unsigned int)h << 16);
}
__device__ __forceinline__ void split2(float v, unsigned short& hi, unsigned short& lo) {
    unsigned short h = bf16_rne(v);
    hi = h;
    lo = bf16_rne(v - bf16_f32(h));
}

// ---------------- utility kernels ----------------
__global__ void k_zero_i32(int* __restrict__ p, int n) {
    int i = blockIdx.x * blockDim.x + threadIdx.x;
    if (i < n) p[i] = 0;
}

__global__ void k_copy_i32(int* __restrict__ d, const int* __restrict__ s, int n) {
    int i = blockIdx.x * blockDim.x + threadIdx.x;
    if (i < n) d[i] = s[i];
}

// ---------------- CSR build over dst ----------------
__global__ void k_count(const int* __restrict__ dst, int* __restrict__ cnt) {
    int i = blockIdx.x * blockDim.x + threadIdx.x;
    if (i < N_EDGES) atomicAdd(&cnt[dst[i]], 1);
}

__global__ void k_scan(const int* __restrict__ cnt, int* __restrict__ off) {
    __shared__ int tsum[256];
    const int CH = (N_NODES + 255) / 256;
    int t = threadIdx.x;
    int s = 0;
    for (int i = 0; i < CH; ++i) {
        int idx = t * CH + i;
        if (idx < N_NODES) s += cnt[idx];
    }
    tsum[t] = s;
    __syncthreads();
    if (t == 0) {
        int acc = 0;
        for (int i = 0; i < 256; ++i) { int v = tsum[i]; tsum[i] = acc; acc += v; }
    }
    __syncthreads();
    int run = tsum[t];
    for (int i = 0; i < CH; ++i) {
        int idx = t * CH + i;
        if (idx < N_NODES) { off[idx] = run; run += cnt[idx]; }
    }
    if (t == 255) off[N_NODES] = run;
}

__global__ void k_fill(const int* __restrict__ dst, int* __restrict__ cursor,
                       int* __restrict__ csr_e) {
    int i = blockIdx.x * blockDim.x + threadIdx.x;
    if (i < N_EDGES) {
        int p = atomicAdd(&cursor[dst[i]], 1);
        csr_e[p] = i;
    }
}

__global__ void k_sort_buckets(const int* __restrict__ off, int* __restrict__ csr_e) {
    int n = blockIdx.x * blockDim.x + threadIdx.x;
    if (n >= N_NODES) return;
    int b = off[n], e = off[n + 1];
    for (int i = b + 1; i < e; ++i) {
        int v = csr_e[i];
        int j = i - 1;
        while (j >= b && csr_e[j] > v) { csr_e[j + 1] = csr_e[j]; --j; }
        csr_e[j + 1] = v;
    }
}

__global__ void k_gstart(const int* __restrict__ gid, int* __restrict__ gstart) {
    int g = blockIdx.x * blockDim.x + threadIdx.x;
    if (g > N_GRAPHS) return;
    int lo = 0, hi = N_NODES;
    while (lo < hi) {
        int mid = (lo + hi) >> 1;
        if (gid[mid] < g) lo = mid + 1; else hi = mid;
    }
    gstart[g] = lo;
}

// ---------------- conversions for split-bf16 GEMM ----------------
// h [20000][63] f32 -> xh/xl [N_PAD][64] bf16 (zero-padded rows & col 63)
__global__ void k_cvt_h(const float* __restrict__ h, unsigned short* __restrict__ xh,
                        unsigned short* __restrict__ xl) {
    int idx = blockIdx.x * 256 + threadIdx.x;
    if (idx >= N_PAD * 64) return;
    int m = idx >> 6, k = idx & 63;
    float v = (m < N_NODES && k < IN_F) ? h[m * IN_F + k] : 0.f;
    unsigned short hi, lo;
    split2(v, hi, lo);
    xh[idx] = hi;
    xl[idx] = lo;
}

// zero pad rows [N_NODES, N_PAD) of the stride-1024 hi/lo buffers (layers 2/3)
__global__ void k_zero_pad(unsigned short* __restrict__ xh, unsigned short* __restrict__ xl) {
    int idx = blockIdx.x * 256 + threadIdx.x;
    const int total = (N_PAD - N_NODES) * F;
    if (idx < total) {
        xh[(size_t)N_NODES * F + idx] = 0;
        xl[(size_t)N_NODES * F + idx] = 0;
    }
}

// W [K][1024] f32 -> W^T hi/lo [1024][Kpad] bf16 (transposed, zero-padded K)
__global__ void k_cvt_w(const float* __restrict__ W, unsigned short* __restrict__ wh,
                        unsigned short* __restrict__ wl, int K, int Kpad) {
    __shared__ float t[32][33];
    int kt = blockIdx.x * 32, nt = blockIdx.y * 32;
    int tx = threadIdx.x & 31, ty = threadIdx.x >> 5;
#pragma unroll
    for (int j = 0; j < 4; ++j) {
        int k = kt + ty + j * 8;
        t[ty + j * 8][tx] = (k < K) ? W[(size_t)k * F + nt + tx] : 0.f;
    }
    __syncthreads();
#pragma unroll
    for (int j = 0; j < 4; ++j) {
        int n = nt + ty + j * 8;
        unsigned short hi, lo;
        split2(t[tx][ty + j * 8], hi, lo);
        wh[(size_t)n * Kpad + kt + tx] = hi;
        wl[(size_t)n * Kpad + kt + tx] = lo;
    }
}

// ---------------- split-bf16 MFMA GEMM ----------------
// C[row][col] = sum_k (Ah+Al)[row][k] * (Bh+Bl)[k][col] + bias[col]
// A*: [N_PAD][Kpad] bf16 row-major. B*: W^T [1024][Kpad] bf16 (B[k][col] = Bt[col][k]).
// 3 products kept: Ah*Bh + Ah*Bl + Al*Bh. grid = (F/128, N_PAD/128), 256 threads.
#define AS1C(p) ((const __attribute__((address_space(1))) void*)(p))
#define AS3(p)  ((__attribute__((address_space(3))) void*)(p))

__launch_bounds__(256, 3)
__global__ void k_gemm_mfma(const unsigned short* __restrict__ Ah, const unsigned short* __restrict__ Al,
                            const unsigned short* __restrict__ Bh, const unsigned short* __restrict__ Bl,
                            const float* __restrict__ bias, float* __restrict__ C, int Kpad) {
    __shared__ unsigned short lds[16384];   // 4 tiles x [128][32] bf16 = 32 KiB
    const int tid = threadIdx.x;
    const int l = tid & 63, w = tid >> 6;
    const int by = blockIdx.y, bx = blockIdx.x;

    // --- staging addresses: wave w stages rows [w*32, w*32+32) of each tile ---
    const int srow = w * 32 + (l >> 2);          // 0..127 (16 rows per 1KB call)
    const int schunk = (l & 3) * 8;              // 16B chunk within 64B row
    const unsigned short* gAh0 = Ah + (size_t)(by * 128 + srow) * Kpad + schunk;
    const unsigned short* gAh1 = gAh0 + (size_t)16 * Kpad;
    const unsigned short* gAl0 = Al + (size_t)(by * 128 + srow) * Kpad + schunk;
    const unsigned short* gAl1 = gAl0 + (size_t)16 * Kpad;
    const unsigned short* gBh0 = Bh + (size_t)(bx * 128 + srow) * Kpad + schunk;
    const unsigned short* gBh1 = gBh0 + (size_t)16 * Kpad;
    const unsigned short* gBl0 = Bl + (size_t)(bx * 128 + srow) * Kpad + schunk;
    const unsigned short* gBl1 = gBl0 + (size_t)16 * Kpad;

    unsigned short* sAh0 = lds + 0 * 4096 + w * 1024;  unsigned short* sAh1 = sAh0 + 512;
    unsigned short* sAl0 = lds + 1 * 4096 + w * 1024;  unsigned short* sAl1 = sAl0 + 512;
    unsigned short* sBh0 = lds + 2 * 4096 + w * 1024;  unsigned short* sBh1 = sBh0 + 512;
    unsigned short* sBl0 = lds + 3 * 4096 + w * 1024;  unsigned short* sBl1 = sBl0 + 512;

    // --- fragment read coords: wave (wr,wc) owns a 64x64 sub-tile ---
    const int wr = (w >> 1) * 64, wc = (w & 1) * 64;
    const int frow = l & 15;
    const int fko = (l >> 4) * 8;                // k chunk: 8 consecutive bf16

    f32x4 acc[4][4];
    const f32x4 fzero = {0.f, 0.f, 0.f, 0.f};
#pragma unroll
    for (int i = 0; i < 4; ++i)
#pragma unroll
        for (int j = 0; j < 4; ++j) acc[i][j] = fzero;

    for (int k0 = 0; k0 < Kpad; k0 += 32) {
        __builtin_amdgcn_global_load_lds(AS1C(gAh0 + k0), AS3(sAh0), 16, 0, 0);
        __builtin_amdgcn_global_load_lds(AS1C(gAh1 + k0), AS3(sAh1), 16, 0, 0);
        __builtin_amdgcn_global_load_lds(AS1C(gAl0 + k0), AS3(sAl0), 16, 0, 0);
        __builtin_amdgcn_global_load_lds(AS1C(gAl1 + k0), AS3(sAl1), 16, 0, 0);
        __builtin_amdgcn_global_load_lds(AS1C(gBh0 + k0), AS3(sBh0), 16, 0, 0);
        __builtin_amdgcn_global_load_lds(AS1C(gBh1 + k0), AS3(sBh1), 16, 0, 0);
        __builtin_amdgcn_global_load_lds(AS1C(gBl0 + k0), AS3(sBl0), 16, 0, 0);
        __builtin_amdgcn_global_load_lds(AS1C(gBl1 + k0), AS3(sBl1), 16, 0, 0);
        __syncthreads();

        short8v a_h[4], a_l[4];
#pragma unroll
        for (int mi = 0; mi < 4; ++mi) {
            int ai = (wr + mi * 16 + frow) * 32 + fko;
            a_h[mi] = *(const short8v*)&lds[ai];
            a_l[mi] = *(const short8v*)&lds[4096 + ai];
        }
#pragma unroll
        for (int ni = 0; ni < 4; ++ni) {
            int bi = (wc + ni * 16 + frow) * 32 + fko;
            short8v b_h = *(const short8v*)&lds[8192 + bi];
            short8v b_l = *(const short8v*)&lds[12288 + bi];
#pragma unroll
            for (int mi = 0; mi < 4; ++mi) {
                acc[mi][ni] = __builtin_amdgcn_mfma_f32_16x16x32_bf16(a_h[mi], b_h, acc[mi][ni], 0, 0, 0);
                acc[mi][ni] = __builtin_amdgcn_mfma_f32_16x16x32_bf16(a_h[mi], b_l, acc[mi][ni], 0, 0, 0);
                acc[mi][ni] = __builtin_amdgcn_mfma_f32_16x16x32_bf16(a_l[mi], b_h, acc[mi][ni], 0, 0, 0);
            }
        }
        __syncthreads();
    }

    // epilogue: C/D layout col = lane&15, row = (lane>>4)*4 + reg
    const int crow0 = by * 128 + wr + (l >> 4) * 4;
    const int ccol = bx * 128 + wc + (l & 15);
#pragma unroll
    for (int mi = 0; mi < 4; ++mi) {
#pragma unroll
        for (int r = 0; r < 4; ++r) {
            int row = crow0 + mi * 16 + r;
            if (row < N_NODES) {
#pragma unroll
                for (int ni = 0; ni < 4; ++ni) {
                    int col = ccol + ni * 16;
                    C[(size_t)row * F + col] = acc[mi][ni][r] + bias[col];
                }
            }
        }
    }
}

// ---------------- edge scores: sc[e,h] = sum_d attn[h,d]*lrelu02(fs[src]+fd[dst]) ----------------
__launch_bounds__(256)
__global__ void k_edge(const float* __restrict__ fs, const float* __restrict__ fd,
                       const int* __restrict__ src, const int* __restrict__ dst,
                       const float* __restrict__ attn, float* __restrict__ sc) {
    int g = blockIdx.x * blockDim.x + threadIdx.x;
    int e = g >> 6;
    int lane = g & 63;
    if (e >= N_EDGES) return;
    int s = src[e], d = dst[e];
    const float4* ps = (const float4*)(fs + (size_t)s * F) + lane * 4;
    const float4* pd = (const float4*)(fd + (size_t)d * F) + lane * 4;
    const float4* pa = (const float4*)attn + lane * 4;
    float acc = 0.f;
#pragma unroll
    for (int j = 0; j < 4; ++j) {
        float4 a = ps[j], b = pd[j], wv = pa[j];
        float v;
        v = a.x + b.x; v = v > 0.f ? v : 0.2f * v; acc += v * wv.x;
        v = a.y + b.y; v = v > 0.f ? v : 0.2f * v; acc += v * wv.y;
        v = a.z + b.z; v = v > 0.f ? v : 0.2f * v; acc += v * wv.z;
        v = a.w + b.w; v = v > 0.f ? v : 0.2f * v; acc += v * wv.w;
    }
    acc += __shfl_xor(acc, 1);
    acc += __shfl_xor(acc, 2);
    acc += __shfl_xor(acc, 4);
    if ((lane & 7) == 0) sc[e * NHEAD + (lane >> 3)] = acc;
}

// ---------------- per-node softmax + aggregation (+bias) ----------------
__launch_bounds__(256)
__global__ void k_agg(const float* __restrict__ fs, const float* __restrict__ sc,
                      const int* __restrict__ off, const int* __restrict__ csr_e,
                      const int* __restrict__ src, const float* __restrict__ bias,
                      float* __restrict__ y) {
    int n = blockIdx.x;
    int t = threadIdx.x;
    __shared__ float sm[NHEAD], sinv[NHEAD];
    int b = off[n], e = off[n + 1];
    if (t < NHEAD) {
        float mm = -1e30f;
        for (int i = b; i < e; ++i) mm = fmaxf(mm, sc[csr_e[i] * NHEAD + t]);
        float den = 0.f;
        for (int i = b; i < e; ++i) den += __expf(sc[csr_e[i] * NHEAD + t] - mm);
        sm[t] = mm;
        sinv[t] = (e > b) ? 1.f / den : 0.f;
    }
    __syncthreads();
    int h = t >> 5;
    float mh = sm[h], ih = sinv[h];
    float ax = 0.f, ay = 0.f, az = 0.f, aw = 0.f;
    for (int i = b; i < e; ++i) {
        int ed = csr_e[i];
        float alpha = __expf(sc[ed * NHEAD + h] - mh) * ih;
        float4 v = *(const float4*)(fs + (size_t)src[ed] * F + t * 4);
        ax += alpha * v.x; ay += alpha * v.y; az += alpha * v.z; aw += alpha * v.w;
    }
    const float4 bb = *(const float4*)(bias + t * 4);
    float4 o;
    o.x = ax + bb.x; o.y = ay + bb.y; o.z = az + bb.z; o.w = aw + bb.w;
    *(float4*)(y + (size_t)n * F + t * 4) = o;
}

// ---------------- BatchNorm (2-stage deterministic) + lrelu + bf16 split ----------------
__global__ void k_bnpart(const float* __restrict__ y, float* __restrict__ part) {
    const int ROWS = (N_NODES + BN_CHUNKS - 1) / BN_CHUNKS;
    int blk = blockIdx.x;
    int t = threadIdx.x;
    int r0 = blk * ROWS;
    int r1 = r0 + ROWS; if (r1 > N_NODES) r1 = N_NODES;
    float sx = 0.f, sy = 0.f, sz = 0.f, sw = 0.f;
    float qx = 0.f, qy = 0.f, qz = 0.f, qw = 0.f;
    for (int r = r0; r < r1; ++r) {
        float4 v = *(const float4*)(y + (size_t)r * F + t * 4);
        sx += v.x; sy += v.y; sz += v.z; sw += v.w;
        qx += v.x * v.x; qy += v.y * v.y; qz += v.z * v.z; qw += v.w * v.w;
    }
    float4 s4; s4.x = sx; s4.y = sy; s4.z = sz; s4.w = sw;
    float4 q4; q4.x = qx; q4.y = qy; q4.z = qz; q4.w = qw;
    *(float4*)(part + (size_t)blk * (2 * F) + t * 4) = s4;
    *(float4*)(part + (size_t)blk * (2 * F) + F + t * 4) = q4;
}

__global__ void k_bnfin(const float* __restrict__ part, const float* __restrict__ gamma,
                        const float* __restrict__ beta, float* __restrict__ scale,
                        float* __restrict__ shift) {
    int c = blockIdx.x * blockDim.x + threadIdx.x;
    if (c >= F) return;
    float s = 0.f, q = 0.f;
    for (int b = 0; b < BN_CHUNKS; ++b) {
        s += part[(size_t)b * (2 * F) + c];
        q += part[(size_t)b * (2 * F) + F + c];
    }
    float mu = s / (float)N_NODES;
    float var = q / (float)N_NODES - mu * mu;
    float sc = gamma[c] * rsqrtf(var + BN_EPS);
    scale[c] = sc;
    shift[c] = beta[c] - mu * sc;
}

// in-place BN+lrelu on y; also emits bf16 hi/lo split for next layer's GEMM
__global__ void k_bnapply(const float* y, const float* __restrict__ scale,
                          const float* __restrict__ shift, float* x,
                          unsigned short* __restrict__ xh, unsigned short* __restrict__ xl) {
    int i = blockIdx.x * blockDim.x + threadIdx.x;
    if (i >= N_NODES * (F / 4)) return;
    int c4 = (i & (F / 4 - 1)) * 4;
    float4 v = ((const float4*)y)[i];
    float4 o;
    o.x = v.x * scale[c4 + 0] + shift[c4 + 0];
    o.y = v.y * scale[c4 + 1] + shift[c4 + 1];
    o.z = v.z * scale[c4 + 2] + shift[c4 + 2];
    o.w = v.w * scale[c4 + 3] + shift[c4 + 3];
    o.x = o.x > 0.f ? o.x : 0.01f * o.x;
    o.y = o.y > 0.f ? o.y : 0.01f * o.y;
    o.z = o.z > 0.f ? o.z : 0.01f * o.z;
    o.w = o.w > 0.f ? o.w : 0.01f * o.w;
    ((float4*)x)[i] = o;
    ushort4v h4, l4;
    unsigned short hh, ll;
    split2(o.x, hh, ll); h4.x = hh; l4.x = ll;
    split2(o.y, hh, ll); h4.y = hh; l4.y = ll;
    split2(o.z, hh, ll); h4.z = hh; l4.z = ll;
    split2(o.w, hh, ll); h4.w = hh; l4.w = ll;
    *(ushort4v*)&xh[(size_t)i * 4] = h4;
    *(ushort4v*)&xl[(size_t)i * 4] = l4;
}

// ---------------- avg pool per graph ----------------
__global__ void k_pool(const float* __restrict__ x, const int* __restrict__ gstart,
                       float* __restrict__ hg) {
    int g = blockIdx.x;
    int t = threadIdx.x;
    int r0 = gstart[g], r1 = gstart[g + 1];
    float sx = 0.f, sy = 0.f, sz = 0.f, sw = 0.f;
    for (int r = r0; r < r1; ++r) {
        float4 v = *(const float4*)(x + (size_t)r * F + t * 4);
        sx += v.x; sy += v.y; sz += v.z; sw += v.w;
    }
    float inv = (r1 > r0) ? 1.f / (float)(r1 - r0) : 0.f;
    float4 o; o.x = sx * inv; o.y = sy * inv; o.z = sz * inv; o.w = sw * inv;
    *(float4*)(hg + (size_t)g * F + t * 4) = o;
}

// ---------------- small MLP GEMM (M=64 rows) ----------------
__global__ void k_mlp(const float* __restrict__ X, const float* __restrict__ W,
                      const float* __restrict__ b, float* __restrict__ out,
                      int K, int Nout, int act) {
    __shared__ float xs[1024];
    int row = blockIdx.y;
    int col = blockIdx.x * 256 + threadIdx.x;
    for (int k = threadIdx.x; k < K; k += 256) xs[k] = X[(size_t)row * K + k];
    __syncthreads();
    if (col < Nout) {
        float acc = b[col];
        for (int k = 0; k < K; ++k) acc += xs[k] * W[(size_t)k * Nout + col];
        if (act && acc < 0.f) acc *= 0.01f;
        out[(size_t)row * Nout + col] = acc;
    }
}

// ---------------- host orchestration ----------------
extern "C" void kernel_launch(void* const* d_in, const int* in_sizes, int n_in,
                              void* d_out, int out_size, void* d_ws, size_t ws_size,
                              hipStream_t stream) {
    const float* h = (const float*)d_in[0];
    const int* src = (const int*)d_in[1];
    const int* dst = (const int*)d_in[2];
    const int* gid = (const int*)d_in[3];

    const float *w_src[3], *b_src[3], *w_dst[3], *b_dst[3], *attn[3], *bias[3], *gamma[3], *beta[3];
    for (int l = 0; l < 3; ++l) {
        int base = 4 + l * 8;
        w_src[l] = (const float*)d_in[base + 0];
        b_src[l] = (const float*)d_in[base + 1];
        w_dst[l] = (const float*)d_in[base + 2];
        b_dst[l] = (const float*)d_in[base + 3];
        attn[l]  = (const float*)d_in[base + 4];
        bias[l]  = (const float*)d_in[base + 5];
        gamma[l] = (const float*)d_in[base + 6];
        beta[l]  = (const float*)d_in[base + 7];
    }
    const float* fc1_w = (const float*)d_in[28];
    const float* fc1_b = (const float*)d_in[29];
    const float* fc2_w = (const float*)d_in[30];
    const float* fc2_b = (const float*)d_in[31];
    const float* fc3_w = (const float*)d_in[32];
    const float* fc3_b = (const float*)d_in[33];

    // workspace carve
    char* base = (char*)d_ws;
    size_t o = 0;
    auto carve = [&](size_t bytes) -> char* {
        char* p = base + o;
        o += (bytes + 255) & ~(size_t)255;
        return p;
    };
    float* fs = (float*)carve((size_t)N_NODES * F * 4);
    float* fd = (float*)carve((size_t)N_NODES * F * 4);   // also y, also final x (in-place BN)
    unsigned short* xh = (unsigned short*)carve((size_t)N_PAD * F * 2);
    unsigned short* xl = (unsigned short*)carve((size_t)N_PAD * F * 2);
    unsigned short* wsh = (unsigned short*)carve((size_t)F * F * 2);
    unsigned short* wsl = (unsigned short*)carve((size_t)F * F * 2);
    unsigned short* wdh = (unsigned short*)carve((size_t)F * F * 2);
    unsigned short* wdl = (unsigned short*)carve((size_t)F * F * 2);
    float* sc = (float*)carve((size_t)N_EDGES * NHEAD * 4);
    int* cnt = (int*)carve((size_t)N_NODES * 4);
    int* off = (int*)carve((size_t)(N_NODES + 1) * 4);
    int* cursor = (int*)carve((size_t)N_NODES * 4);
    int* csr_e = (int*)carve((size_t)N_EDGES * 4);
    float* part = (float*)carve((size_t)BN_CHUNKS * 2 * F * 4);
    float* scale = (float*)carve(F * 4);
    float* shift = (float*)carve(F * 4);
    int* gstart = (int*)carve((N_GRAPHS + 1) * 4);
    float* hg = (float*)carve((size_t)N_GRAPHS * F * 4);
    float* z1 = (float*)carve((size_t)N_GRAPHS * F * 4);
    float* z2 = (float*)carve((size_t)N_GRAPHS * F * 4);
    (void)ws_size;

    // ---- CSR build (deterministic: buckets sorted by edge id) ----
    k_zero_i32<<<(N_NODES + 255) / 256, 256, 0, stream>>>(cnt, N_NODES);
    k_count<<<(N_EDGES + 255) / 256, 256, 0, stream>>>(dst, cnt);
    k_scan<<<1, 256, 0, stream>>>(cnt, off);
    k_copy_i32<<<(N_NODES + 255) / 256, 256, 0, stream>>>(cursor, off, N_NODES);
    k_fill<<<(N_EDGES + 255) / 256, 256, 0, stream>>>(dst, cursor, csr_e);
    k_sort_buckets<<<(N_NODES + 255) / 256, 256, 0, stream>>>(off, csr_e);
    k_gstart<<<1, 128, 0, stream>>>(gid, gstart);

    // ---- input conversion + pad-row zeroing ----
    k_cvt_h<<<(N_PAD * 64 + 255) / 256, 256, 0, stream>>>(h, xh, xl);
    k_zero_pad<<<((N_PAD - N_NODES) * F + 255) / 256, 256, 0, stream>>>(xh, xl);

    // ---- 3 GATv2 + BN + lrelu layers ----
    const dim3 ggrid(F / 128, N_PAD / 128);
    for (int l = 0; l < 3; ++l) {
        const int K = (l == 0) ? IN_F : F;
        const int Kp = (l == 0) ? 64 : F;
        k_cvt_w<<<dim3(Kp / 32, F / 32), 256, 0, stream>>>(w_src[l], wsh, wsl, K, Kp);
        k_cvt_w<<<dim3(Kp / 32, F / 32), 256, 0, stream>>>(w_dst[l], wdh, wdl, K, Kp);
        k_gemm_mfma<<<ggrid, 256, 0, stream>>>(xh, xl, wsh, wsl, b_src[l], fs, Kp);
        k_gemm_mfma<<<ggrid, 256, 0, stream>>>(xh, xl, wdh, wdl, b_dst[l], fd, Kp);
        k_edge<<<(N_EDGES * 64 + 255) / 256, 256, 0, stream>>>(fs, fd, src, dst, attn[l], sc);
        k_agg<<<N_NODES, 256, 0, stream>>>(fs, sc, off, csr_e, src, bias[l], fd);
        k_bnpart<<<BN_CHUNKS, 256, 0, stream>>>(fd, part);
        k_bnfin<<<F / 256, 256, 0, stream>>>(part, gamma[l], beta[l], scale, shift);
        k_bnapply<<<(N_NODES * (F / 4) + 255) / 256, 256, 0, stream>>>(fd, scale, shift, fd, xh, xl);
    }

    // ---- pool + MLP head ----
    k_pool<<<N_GRAPHS, 256, 0, stream>>>(fd, gstart, hg);
    k_mlp<<<dim3(4, N_GRAPHS), 256, 0, stream>>>(hg, fc1_w, fc1_b, z1, F, F, 1);
    k_mlp<<<dim3(4, N_GRAPHS), 256, 0, stream>>>(z1, fc2_w, fc2_b, z2, F, F, 1);
    k_mlp<<<dim3(1, N_GRAPHS), 256, 0, stream>>>(z2, fc3_w, fc3_b, (float*)d_out, F, NCLS, 0);
}

// Round 3
// 1503.504 us; speedup vs baseline: 2.4076x; 1.2720x over previous
//
#include <hip/hip_runtime.h>
#include <math.h>

#define N_NODES 20000
#define N_PAD   20096            // 157 * 128
#define N_EDGES 100000
#define N_GRAPHS 64
#define IN_F 63
#define NHEAD 8
#define F 1024                   // NHEAD * HID
#define NCLS 18
#define BN_EPS 1e-5f
#define BN_CHUNKS 128

typedef __attribute__((ext_vector_type(8))) short short8v;   // 8 bf16 (4 VGPRs)
typedef __attribute__((ext_vector_type(4))) float f32x4;
typedef __attribute__((ext_vector_type(4))) unsigned short ushort4v;

__device__ __forceinline__ unsigned short bf16_rne(float f) {
    unsigned int u = __float_as_uint(f);
    u += 0x7fff + ((u >> 16) & 1);
    return (unsigned short)(u >> 16);
}
__device__ __forceinline__ float bf16_f32(unsigned short h) {
    return __uint_as_float((unsigned int)h << 16);
}
__device__ __forceinline__ void split2(float v, unsigned short& hi, unsigned short& lo) {
    unsigned short h = bf16_rne(v);
    hi = h;
    lo = bf16_rne(v - bf16_f32(h));
}

// ---------------- utility kernels ----------------
__global__ void k_zero_i32(int* __restrict__ p, int n) {
    int i = blockIdx.x * blockDim.x + threadIdx.x;
    if (i < n) p[i] = 0;
}

__global__ void k_copy_i32(int* __restrict__ d, const int* __restrict__ s, int n) {
    int i = blockIdx.x * blockDim.x + threadIdx.x;
    if (i < n) d[i] = s[i];
}

// ---------------- CSR build over dst ----------------
__global__ void k_count(const int* __restrict__ dst, int* __restrict__ cnt) {
    int i = blockIdx.x * blockDim.x + threadIdx.x;
    if (i < N_EDGES) atomicAdd(&cnt[dst[i]], 1);
}

__global__ void k_scan(const int* __restrict__ cnt, int* __restrict__ off) {
    __shared__ int tsum[256];
    const int CH = (N_NODES + 255) / 256;
    int t = threadIdx.x;
    int s = 0;
    for (int i = 0; i < CH; ++i) {
        int idx = t * CH + i;
        if (idx < N_NODES) s += cnt[idx];
    }
    tsum[t] = s;
    __syncthreads();
    if (t == 0) {
        int acc = 0;
        for (int i = 0; i < 256; ++i) { int v = tsum[i]; tsum[i] = acc; acc += v; }
    }
    __syncthreads();
    int run = tsum[t];
    for (int i = 0; i < CH; ++i) {
        int idx = t * CH + i;
        if (idx < N_NODES) { off[idx] = run; run += cnt[idx]; }
    }
    if (t == 255) off[N_NODES] = run;
}

__global__ void k_fill(const int* __restrict__ dst, int* __restrict__ cursor,
                       int* __restrict__ csr_e) {
    int i = blockIdx.x * blockDim.x + threadIdx.x;
    if (i < N_EDGES) {
        int p = atomicAdd(&cursor[dst[i]], 1);
        csr_e[p] = i;
    }
}

__global__ void k_sort_buckets(const int* __restrict__ off, int* __restrict__ csr_e) {
    int n = blockIdx.x * blockDim.x + threadIdx.x;
    if (n >= N_NODES) return;
    int b = off[n], e = off[n + 1];
    for (int i = b + 1; i < e; ++i) {
        int v = csr_e[i];
        int j = i - 1;
        while (j >= b && csr_e[j] > v) { csr_e[j + 1] = csr_e[j]; --j; }
        csr_e[j + 1] = v;
    }
}

__global__ void k_gstart(const int* __restrict__ gid, int* __restrict__ gstart) {
    int g = blockIdx.x * blockDim.x + threadIdx.x;
    if (g > N_GRAPHS) return;
    int lo = 0, hi = N_NODES;
    while (lo < hi) {
        int mid = (lo + hi) >> 1;
        if (gid[mid] < g) lo = mid + 1; else hi = mid;
    }
    gstart[g] = lo;
}

// ---------------- conversions for split-bf16 GEMM ----------------
__global__ void k_cvt_h(const float* __restrict__ h, unsigned short* __restrict__ xh,
                        unsigned short* __restrict__ xl) {
    int idx = blockIdx.x * 256 + threadIdx.x;
    if (idx >= N_PAD * 64) return;
    int m = idx >> 6, k = idx & 63;
    float v = (m < N_NODES && k < IN_F) ? h[m * IN_F + k] : 0.f;
    unsigned short hi, lo;
    split2(v, hi, lo);
    xh[idx] = hi;
    xl[idx] = lo;
}

__global__ void k_zero_pad(unsigned short* __restrict__ xh, unsigned short* __restrict__ xl) {
    int idx = blockIdx.x * 256 + threadIdx.x;
    const int total = (N_PAD - N_NODES) * F;
    if (idx < total) {
        xh[(size_t)N_NODES * F + idx] = 0;
        xl[(size_t)N_NODES * F + idx] = 0;
    }
}

// W [K][1024] f32 -> W^T hi/lo [1024][Kpad] bf16 (transposed, zero-padded K)
__global__ void k_cvt_w(const float* __restrict__ W, unsigned short* __restrict__ wh,
                        unsigned short* __restrict__ wl, int K, int Kpad) {
    __shared__ float t[32][33];
    int kt = blockIdx.x * 32, nt = blockIdx.y * 32;
    int tx = threadIdx.x & 31, ty = threadIdx.x >> 5;
#pragma unroll
    for (int j = 0; j < 4; ++j) {
        int k = kt + ty + j * 8;
        t[ty + j * 8][tx] = (k < K) ? W[(size_t)k * F + nt + tx] : 0.f;
    }
    __syncthreads();
#pragma unroll
    for (int j = 0; j < 4; ++j) {
        int n = nt + ty + j * 8;
        unsigned short hi, lo;
        split2(t[tx][ty + j * 8], hi, lo);
        wh[(size_t)n * Kpad + kt + tx] = hi;
        wl[(size_t)n * Kpad + kt + tx] = lo;
    }
}

// ---------------- fused dual split-bf16 MFMA GEMM ----------------
// Computes fs = A@Ws + bs  AND  fd = A@Wd + bd in one pass (shared A tiles).
// A*: [N_PAD][Kpad] bf16 row-major. B*: W^T [1024][Kpad] bf16.
// 3 products: Ah*Bh + Ah*Bl + Al*Bh. grid = (8, N_PAD/128), 256 threads.
#define AS1C(p) ((const __attribute__((address_space(1))) void*)(p))
#define AS3(p)  ((__attribute__((address_space(3))) void*)(p))

__launch_bounds__(256, 2)
__global__ void k_gemm_dual(const unsigned short* __restrict__ Ah, const unsigned short* __restrict__ Al,
                            const unsigned short* __restrict__ Bsh, const unsigned short* __restrict__ Bsl,
                            const unsigned short* __restrict__ Bdh, const unsigned short* __restrict__ Bdl,
                            const float* __restrict__ bias_s, const float* __restrict__ bias_d,
                            float* __restrict__ Cs, float* __restrict__ Cd, int Kpad) {
    __shared__ unsigned short lds[24576];   // 6 tiles x [128][32] bf16 = 48 KiB
    const int tid = threadIdx.x;
    const int l = tid & 63, w = tid >> 6;

    // XCD-aware bijective swizzle: nwg = 8*157 = 1256, 1256 % 8 == 0
    const int orig = blockIdx.y * 8 + blockIdx.x;
    const int wg = (orig & 7) * (N_PAD / 128) + (orig >> 3);
    const int by = wg >> 3, bx = wg & 7;

    // --- staging: wave w stages rows [w*32, w*32+32) of each tile, 2 calls/tile ---
    const int srow = w * 32 + (l >> 2);
    const int scol = (l & 3) * 8;
    const size_t aoff = (size_t)(by * 128 + srow) * Kpad + scol;
    const size_t boff = (size_t)(bx * 128 + srow) * Kpad + scol;
    const size_t step = (size_t)16 * Kpad;
    const unsigned short* gAh = Ah + aoff;
    const unsigned short* gAl = Al + aoff;
    const unsigned short* gBsh = Bsh + boff;
    const unsigned short* gBsl = Bsl + boff;
    const unsigned short* gBdh = Bdh + boff;
    const unsigned short* gBdl = Bdl + boff;

    unsigned short* sAh = lds + 0 * 4096 + w * 1024;
    unsigned short* sAl = lds + 1 * 4096 + w * 1024;
    unsigned short* sBsh = lds + 2 * 4096 + w * 1024;
    unsigned short* sBsl = lds + 3 * 4096 + w * 1024;
    unsigned short* sBdh = lds + 4 * 4096 + w * 1024;
    unsigned short* sBdl = lds + 5 * 4096 + w * 1024;

    // --- fragment coords: wave (wr,wc) owns a 64x64 sub-tile of each output ---
    const int wr = (w >> 1) * 64, wc = (w & 1) * 64;
    const int frow = l & 15;
    const int fko = (l >> 4) * 8;

    f32x4 accS[4][4], accD[4][4];
    const f32x4 fzero = {0.f, 0.f, 0.f, 0.f};
#pragma unroll
    for (int i = 0; i < 4; ++i)
#pragma unroll
        for (int j = 0; j < 4; ++j) { accS[i][j] = fzero; accD[i][j] = fzero; }

    for (int k0 = 0; k0 < Kpad; k0 += 32) {
        __builtin_amdgcn_global_load_lds(AS1C(gAh + k0), AS3(sAh), 16, 0, 0);
        __builtin_amdgcn_global_load_lds(AS1C(gAh + step + k0), AS3(sAh + 512), 16, 0, 0);
        __builtin_amdgcn_global_load_lds(AS1C(gAl + k0), AS3(sAl), 16, 0, 0);
        __builtin_amdgcn_global_load_lds(AS1C(gAl + step + k0), AS3(sAl + 512), 16, 0, 0);
        __builtin_amdgcn_global_load_lds(AS1C(gBsh + k0), AS3(sBsh), 16, 0, 0);
        __builtin_amdgcn_global_load_lds(AS1C(gBsh + step + k0), AS3(sBsh + 512), 16, 0, 0);
        __builtin_amdgcn_global_load_lds(AS1C(gBsl + k0), AS3(sBsl), 16, 0, 0);
        __builtin_amdgcn_global_load_lds(AS1C(gBsl + step + k0), AS3(sBsl + 512), 16, 0, 0);
        __builtin_amdgcn_global_load_lds(AS1C(gBdh + k0), AS3(sBdh), 16, 0, 0);
        __builtin_amdgcn_global_load_lds(AS1C(gBdh + step + k0), AS3(sBdh + 512), 16, 0, 0);
        __builtin_amdgcn_global_load_lds(AS1C(gBdl + k0), AS3(sBdl), 16, 0, 0);
        __builtin_amdgcn_global_load_lds(AS1C(gBdl + step + k0), AS3(sBdl + 512), 16, 0, 0);
        __syncthreads();

        short8v a_h[4], a_l[4];
#pragma unroll
        for (int mi = 0; mi < 4; ++mi) {
            int ai = (wr + mi * 16 + frow) * 32 + fko;
            a_h[mi] = *(const short8v*)&lds[ai];
            a_l[mi] = *(const short8v*)&lds[4096 + ai];
        }
#pragma unroll
        for (int ni = 0; ni < 4; ++ni) {
            int bi = (wc + ni * 16 + frow) * 32 + fko;
            short8v bs_h = *(const short8v*)&lds[8192 + bi];
            short8v bs_l = *(const short8v*)&lds[12288 + bi];
            short8v bd_h = *(const short8v*)&lds[16384 + bi];
            short8v bd_l = *(const short8v*)&lds[20480 + bi];
#pragma unroll
            for (int mi = 0; mi < 4; ++mi) {
                accS[mi][ni] = __builtin_amdgcn_mfma_f32_16x16x32_bf16(a_h[mi], bs_h, accS[mi][ni], 0, 0, 0);
                accS[mi][ni] = __builtin_amdgcn_mfma_f32_16x16x32_bf16(a_h[mi], bs_l, accS[mi][ni], 0, 0, 0);
                accS[mi][ni] = __builtin_amdgcn_mfma_f32_16x16x32_bf16(a_l[mi], bs_h, accS[mi][ni], 0, 0, 0);
                accD[mi][ni] = __builtin_amdgcn_mfma_f32_16x16x32_bf16(a_h[mi], bd_h, accD[mi][ni], 0, 0, 0);
                accD[mi][ni] = __builtin_amdgcn_mfma_f32_16x16x32_bf16(a_h[mi], bd_l, accD[mi][ni], 0, 0, 0);
                accD[mi][ni] = __builtin_amdgcn_mfma_f32_16x16x32_bf16(a_l[mi], bd_h, accD[mi][ni], 0, 0, 0);
            }
        }
        __syncthreads();
    }

    // epilogue: C/D layout col = lane&15, row = (lane>>4)*4 + reg
    const int crow0 = by * 128 + wr + (l >> 4) * 4;
    const int ccol = bx * 128 + wc + (l & 15);
#pragma unroll
    for (int mi = 0; mi < 4; ++mi) {
#pragma unroll
        for (int r = 0; r < 4; ++r) {
            int row = crow0 + mi * 16 + r;
            if (row < N_NODES) {
#pragma unroll
                for (int ni = 0; ni < 4; ++ni) {
                    int col = ccol + ni * 16;
                    Cs[(size_t)row * F + col] = accS[mi][ni][r] + bias_s[col];
                    Cd[(size_t)row * F + col] = accD[mi][ni][r] + bias_d[col];
                }
            }
        }
    }
}

// ---------------- fused GATv2 edge+softmax+aggregate (online softmax) ----------------
// One block per dst node. fd[n] row read once; each fs[src] row read once and
// reused for both the score and the weighted accumulation. y may alias fd
// (block n only touches fd row n, written after all reads).
__launch_bounds__(256)
__global__ void k_gat(const float* __restrict__ fs, const float* __restrict__ fd,
                      const int* __restrict__ off, const int* __restrict__ csr_e,
                      const int* __restrict__ src, const float* __restrict__ attn,
                      const float* __restrict__ bias, float* __restrict__ y) {
    __shared__ int s_src[256];
    const int n = blockIdx.x;
    const int t = threadIdx.x;
    const int b = off[n], e = off[n + 1];

    const float4 fdv = *(const float4*)(fd + (size_t)n * F + t * 4);
    const float4 av = *(const float4*)(attn + (t >> 5) * 128 + (t & 31) * 4);

    float m = -1e30f, den = 0.f;
    float ax = 0.f, ay = 0.f, az = 0.f, aw = 0.f;

    for (int c0 = b; c0 < e; c0 += 256) {
        int ncur = e - c0; if (ncur > 256) ncur = 256;
        __syncthreads();
        if (t < ncur) s_src[t] = src[csr_e[c0 + t]];
        __syncthreads();
        for (int i = 0; i < ncur; ++i) {
            int s = s_src[i];
            const float4 fsv = *(const float4*)(fs + (size_t)s * F + t * 4);
            float vx = fsv.x + fdv.x; vx = vx > 0.f ? vx : 0.2f * vx;
            float vy = fsv.y + fdv.y; vy = vy > 0.f ? vy : 0.2f * vy;
            float vz = fsv.z + fdv.z; vz = vz > 0.f ? vz : 0.2f * vz;
            float vw = fsv.w + fdv.w; vw = vw > 0.f ? vw : 0.2f * vw;
            float p = vx * av.x + vy * av.y + vz * av.z + vw * av.w;
            p += __shfl_xor(p, 1);
            p += __shfl_xor(p, 2);
            p += __shfl_xor(p, 4);
            p += __shfl_xor(p, 8);
            p += __shfl_xor(p, 16);   // all 32 lanes of the head hold the score
            float mn = fmaxf(m, p);
            float so = __expf(m - mn);    // 0 when m == -1e30
            float wexp = __expf(p - mn);
            den = den * so + wexp;
            ax = ax * so + wexp * fsv.x;
            ay = ay * so + wexp * fsv.y;
            az = az * so + wexp * fsv.z;
            aw = aw * so + wexp * fsv.w;
            m = mn;
        }
    }
    float inv = (e > b) ? 1.f / den : 0.f;
    const float4 bb = *(const float4*)(bias + t * 4);
    float4 o;
    o.x = ax * inv + bb.x;
    o.y = ay * inv + bb.y;
    o.z = az * inv + bb.z;
    o.w = aw * inv + bb.w;
    *(float4*)(y + (size_t)n * F + t * 4) = o;
}

// ---------------- BatchNorm (2-stage deterministic) + lrelu + bf16 split ----------------
__global__ void k_bnpart(const float* __restrict__ y, float* __restrict__ part) {
    const int ROWS = (N_NODES + BN_CHUNKS - 1) / BN_CHUNKS;
    int blk = blockIdx.x;
    int t = threadIdx.x;
    int r0 = blk * ROWS;
    int r1 = r0 + ROWS; if (r1 > N_NODES) r1 = N_NODES;
    float sx = 0.f, sy = 0.f, sz = 0.f, sw = 0.f;
    float qx = 0.f, qy = 0.f, qz = 0.f, qw = 0.f;
    for (int r = r0; r < r1; ++r) {
        float4 v = *(const float4*)(y + (size_t)r * F + t * 4);
        sx += v.x; sy += v.y; sz += v.z; sw += v.w;
        qx += v.x * v.x; qy += v.y * v.y; qz += v.z * v.z; qw += v.w * v.w;
    }
    float4 s4; s4.x = sx; s4.y = sy; s4.z = sz; s4.w = sw;
    float4 q4; q4.x = qx; q4.y = qy; q4.z = qz; q4.w = qw;
    *(float4*)(part + (size_t)blk * (2 * F) + t * 4) = s4;
    *(float4*)(part + (size_t)blk * (2 * F) + F + t * 4) = q4;
}

__global__ void k_bnfin(const float* __restrict__ part, const float* __restrict__ gamma,
                        const float* __restrict__ beta, float* __restrict__ scale,
                        float* __restrict__ shift) {
    int c = blockIdx.x * blockDim.x + threadIdx.x;
    if (c >= F) return;
    float s = 0.f, q = 0.f;
    for (int b = 0; b < BN_CHUNKS; ++b) {
        s += part[(size_t)b * (2 * F) + c];
        q += part[(size_t)b * (2 * F) + F + c];
    }
    float mu = s / (float)N_NODES;
    float var = q / (float)N_NODES - mu * mu;
    float sc = gamma[c] * rsqrtf(var + BN_EPS);
    scale[c] = sc;
    shift[c] = beta[c] - mu * sc;
}

// in-place BN+lrelu on y; emits bf16 hi/lo split for next layer's GEMM
__global__ void k_bnapply(const float* y, const float* __restrict__ scale,
                          const float* __restrict__ shift, float* x,
                          unsigned short* __restrict__ xh, unsigned short* __restrict__ xl) {
    int i = blockIdx.x * blockDim.x + threadIdx.x;
    if (i >= N_NODES * (F / 4)) return;
    int c4 = (i & (F / 4 - 1)) * 4;
    float4 v = ((const float4*)y)[i];
    float4 o;
    o.x = v.x * scale[c4 + 0] + shift[c4 + 0];
    o.y = v.y * scale[c4 + 1] + shift[c4 + 1];
    o.z = v.z * scale[c4 + 2] + shift[c4 + 2];
    o.w = v.w * scale[c4 + 3] + shift[c4 + 3];
    o.x = o.x > 0.f ? o.x : 0.01f * o.x;
    o.y = o.y > 0.f ? o.y : 0.01f * o.y;
    o.z = o.z > 0.f ? o.z : 0.01f * o.z;
    o.w = o.w > 0.f ? o.w : 0.01f * o.w;
    ((float4*)x)[i] = o;
    ushort4v h4, l4;
    unsigned short hh, ll;
    split2(o.x, hh, ll); h4.x = hh; l4.x = ll;
    split2(o.y, hh, ll); h4.y = hh; l4.y = ll;
    split2(o.z, hh, ll); h4.z = hh; l4.z = ll;
    split2(o.w, hh, ll); h4.w = hh; l4.w = ll;
    *(ushort4v*)&xh[(size_t)i * 4] = h4;
    *(ushort4v*)&xl[(size_t)i * 4] = l4;
}

// ---------------- avg pool per graph ----------------
__global__ void k_pool(const float* __restrict__ x, const int* __restrict__ gstart,
                       float* __restrict__ hg) {
    int g = blockIdx.x;
    int t = threadIdx.x;
    int r0 = gstart[g], r1 = gstart[g + 1];
    float sx = 0.f, sy = 0.f, sz = 0.f, sw = 0.f;
    for (int r = r0; r < r1; ++r) {
        float4 v = *(const float4*)(x + (size_t)r * F + t * 4);
        sx += v.x; sy += v.y; sz += v.z; sw += v.w;
    }
    float inv = (r1 > r0) ? 1.f / (float)(r1 - r0) : 0.f;
    float4 o; o.x = sx * inv; o.y = sy * inv; o.z = sz * inv; o.w = sw * inv;
    *(float4*)(hg + (size_t)g * F + t * 4) = o;
}

// ---------------- small MLP GEMM (M=64 rows) ----------------
__global__ void k_mlp(const float* __restrict__ X, const float* __restrict__ W,
                      const float* __restrict__ b, float* __restrict__ out,
                      int K, int Nout, int act) {
    __shared__ float xs[1024];
    int row = blockIdx.y;
    int col = blockIdx.x * 256 + threadIdx.x;
    for (int k = threadIdx.x; k < K; k += 256) xs[k] = X[(size_t)row * K + k];
    __syncthreads();
    if (col < Nout) {
        float acc = b[col];
        for (int k = 0; k < K; ++k) acc += xs[k] * W[(size_t)k * Nout + col];
        if (act && acc < 0.f) acc *= 0.01f;
        out[(size_t)row * Nout + col] = acc;
    }
}

// ---------------- host orchestration ----------------
extern "C" void kernel_launch(void* const* d_in, const int* in_sizes, int n_in,
                              void* d_out, int out_size, void* d_ws, size_t ws_size,
                              hipStream_t stream) {
    const float* h = (const float*)d_in[0];
    const int* src = (const int*)d_in[1];
    const int* dst = (const int*)d_in[2];
    const int* gid = (const int*)d_in[3];

    const float *w_src[3], *b_src[3], *w_dst[3], *b_dst[3], *attn[3], *bias[3], *gamma[3], *beta[3];
    for (int l = 0; l < 3; ++l) {
        int base = 4 + l * 8;
        w_src[l] = (const float*)d_in[base + 0];
        b_src[l] = (const float*)d_in[base + 1];
        w_dst[l] = (const float*)d_in[base + 2];
        b_dst[l] = (const float*)d_in[base + 3];
        attn[l]  = (const float*)d_in[base + 4];
        bias[l]  = (const float*)d_in[base + 5];
        gamma[l] = (const float*)d_in[base + 6];
        beta[l]  = (const float*)d_in[base + 7];
    }
    const float* fc1_w = (const float*)d_in[28];
    const float* fc1_b = (const float*)d_in[29];
    const float* fc2_w = (const float*)d_in[30];
    const float* fc2_b = (const float*)d_in[31];
    const float* fc3_w = (const float*)d_in[32];
    const float* fc3_b = (const float*)d_in[33];

    // workspace carve
    char* base = (char*)d_ws;
    size_t o = 0;
    auto carve = [&](size_t bytes) -> char* {
        char* p = base + o;
        o += (bytes + 255) & ~(size_t)255;
        return p;
    };
    float* fs = (float*)carve((size_t)N_NODES * F * 4);
    float* fd = (float*)carve((size_t)N_NODES * F * 4);   // also y, also final x (in-place BN)
    unsigned short* xh = (unsigned short*)carve((size_t)N_PAD * F * 2);
    unsigned short* xl = (unsigned short*)carve((size_t)N_PAD * F * 2);
    unsigned short* wsh = (unsigned short*)carve((size_t)F * F * 2);
    unsigned short* wsl = (unsigned short*)carve((size_t)F * F * 2);
    unsigned short* wdh = (unsigned short*)carve((size_t)F * F * 2);
    unsigned short* wdl = (unsigned short*)carve((size_t)F * F * 2);
    int* cnt = (int*)carve((size_t)N_NODES * 4);
    int* off = (int*)carve((size_t)(N_NODES + 1) * 4);
    int* cursor = (int*)carve((size_t)N_NODES * 4);
    int* csr_e = (int*)carve((size_t)N_EDGES * 4);
    float* part = (float*)carve((size_t)BN_CHUNKS * 2 * F * 4);
    float* scale = (float*)carve(F * 4);
    float* shift = (float*)carve(F * 4);
    int* gstart = (int*)carve((N_GRAPHS + 1) * 4);
    float* hg = (float*)carve((size_t)N_GRAPHS * F * 4);
    float* z1 = (float*)carve((size_t)N_GRAPHS * F * 4);
    float* z2 = (float*)carve((size_t)N_GRAPHS * F * 4);
    (void)ws_size;

    // ---- CSR build (deterministic: buckets sorted by edge id) ----
    k_zero_i32<<<(N_NODES + 255) / 256, 256, 0, stream>>>(cnt, N_NODES);
    k_count<<<(N_EDGES + 255) / 256, 256, 0, stream>>>(dst, cnt);
    k_scan<<<1, 256, 0, stream>>>(cnt, off);
    k_copy_i32<<<(N_NODES + 255) / 256, 256, 0, stream>>>(cursor, off, N_NODES);
    k_fill<<<(N_EDGES + 255) / 256, 256, 0, stream>>>(dst, cursor, csr_e);
    k_sort_buckets<<<(N_NODES + 255) / 256, 256, 0, stream>>>(off, csr_e);
    k_gstart<<<1, 128, 0, stream>>>(gid, gstart);

    // ---- input conversion + pad-row zeroing ----
    k_cvt_h<<<(N_PAD * 64 + 255) / 256, 256, 0, stream>>>(h, xh, xl);
    k_zero_pad<<<((N_PAD - N_NODES) * F + 255) / 256, 256, 0, stream>>>(xh, xl);

    // ---- 3 GATv2 + BN + lrelu layers ----
    const dim3 ggrid(8, N_PAD / 128);
    for (int l = 0; l < 3; ++l) {
        const int K = (l == 0) ? IN_F : F;
        const int Kp = (l == 0) ? 64 : F;
        k_cvt_w<<<dim3(Kp / 32, F / 32), 256, 0, stream>>>(w_src[l], wsh, wsl, K, Kp);
        k_cvt_w<<<dim3(Kp / 32, F / 32), 256, 0, stream>>>(w_dst[l], wdh, wdl, K, Kp);
        k_gemm_dual<<<ggrid, 256, 0, stream>>>(xh, xl, wsh, wsl, wdh, wdl,
                                               b_src[l], b_dst[l], fs, fd, Kp);
        k_gat<<<N_NODES, 256, 0, stream>>>(fs, fd, off, csr_e, src, attn[l], bias[l], fd);
        k_bnpart<<<BN_CHUNKS, 256, 0, stream>>>(fd, part);
        k_bnfin<<<F / 256, 256, 0, stream>>>(part, gamma[l], beta[l], scale, shift);
        k_bnapply<<<(N_NODES * (F / 4) + 255) / 256, 256, 0, stream>>>(fd, scale, shift, fd, xh, xl);
    }

    // ---- pool + MLP head ----
    k_pool<<<N_GRAPHS, 256, 0, stream>>>(fd, gstart, hg);
    k_mlp<<<dim3(4, N_GRAPHS), 256, 0, stream>>>(hg, fc1_w, fc1_b, z1, F, F, 1);
    k_mlp<<<dim3(4, N_GRAPHS), 256, 0, stream>>>(z1, fc2_w, fc2_b, z2, F, F, 1);
    k_mlp<<<dim3(1, N_GRAPHS), 256, 0, stream>>>(z2, fc3_w, fc3_b, (float*)d_out, F, NCLS, 0);
}

// Round 4
// 1234.648 us; speedup vs baseline: 2.9319x; 1.2178x over previous
//
#include <hip/hip_runtime.h>
#include <math.h>

#define N_NODES 20000
#define N_PAD   20096            // 157 * 128
#define N_EDGES 100000
#define N_GRAPHS 64
#define IN_F 63
#define NHEAD 8
#define F 1024                   // NHEAD * HID
#define NCLS 18
#define BN_EPS 1e-5f
#define BN_CHUNKS 256

typedef __attribute__((ext_vector_type(8))) _Float16 half8v;  // 8 f16 (4 VGPRs)
typedef __attribute__((ext_vector_type(4))) _Float16 half4v;
typedef __attribute__((ext_vector_type(4))) float f32x4;

// ---------------- utility kernels ----------------
__global__ void k_zero_i32(int* __restrict__ p, int n) {
    int i = blockIdx.x * blockDim.x + threadIdx.x;
    if (i < n) p[i] = 0;
}

__global__ void k_copy_i32(int* __restrict__ d, const int* __restrict__ s, int n) {
    int i = blockIdx.x * blockDim.x + threadIdx.x;
    if (i < n) d[i] = s[i];
}

// ---------------- CSR build over dst ----------------
__global__ void k_count(const int* __restrict__ dst, int* __restrict__ cnt) {
    int i = blockIdx.x * blockDim.x + threadIdx.x;
    if (i < N_EDGES) atomicAdd(&cnt[dst[i]], 1);
}

__global__ void k_scan(const int* __restrict__ cnt, int* __restrict__ off) {
    __shared__ int tsum[256];
    const int CH = (N_NODES + 255) / 256;
    int t = threadIdx.x;
    int s = 0;
    for (int i = 0; i < CH; ++i) {
        int idx = t * CH + i;
        if (idx < N_NODES) s += cnt[idx];
    }
    tsum[t] = s;
    __syncthreads();
    if (t == 0) {
        int acc = 0;
        for (int i = 0; i < 256; ++i) { int v = tsum[i]; tsum[i] = acc; acc += v; }
    }
    __syncthreads();
    int run = tsum[t];
    for (int i = 0; i < CH; ++i) {
        int idx = t * CH + i;
        if (idx < N_NODES) { off[idx] = run; run += cnt[idx]; }
    }
    if (t == 255) off[N_NODES] = run;
}

__global__ void k_fill(const int* __restrict__ dst, int* __restrict__ cursor,
                       int* __restrict__ csr_e) {
    int i = blockIdx.x * blockDim.x + threadIdx.x;
    if (i < N_EDGES) {
        int p = atomicAdd(&cursor[dst[i]], 1);
        csr_e[p] = i;
    }
}

__global__ void k_sort_buckets(const int* __restrict__ off, int* __restrict__ csr_e) {
    int n = blockIdx.x * blockDim.x + threadIdx.x;
    if (n >= N_NODES) return;
    int b = off[n], e = off[n + 1];
    for (int i = b + 1; i < e; ++i) {
        int v = csr_e[i];
        int j = i - 1;
        while (j >= b && csr_e[j] > v) { csr_e[j + 1] = csr_e[j]; --j; }
        csr_e[j + 1] = v;
    }
}

__global__ void k_gstart(const int* __restrict__ gid, int* __restrict__ gstart) {
    int g = blockIdx.x * blockDim.x + threadIdx.x;
    if (g > N_GRAPHS) return;
    int lo = 0, hi = N_NODES;
    while (lo < hi) {
        int mid = (lo + hi) >> 1;
        if (gid[mid] < g) lo = mid + 1; else hi = mid;
    }
    gstart[g] = lo;
}

// ---------------- conversions for f16 GEMM ----------------
// h [20000][63] f32 -> xh [N_PAD][64] f16 (zero-padded rows & col 63)
__global__ void k_cvt_h(const float* __restrict__ h, _Float16* __restrict__ xh) {
    int idx = blockIdx.x * 256 + threadIdx.x;
    if (idx >= N_PAD * 64) return;
    int m = idx >> 6, k = idx & 63;
    float v = (m < N_NODES && k < IN_F) ? h[m * IN_F + k] : 0.f;
    xh[idx] = (_Float16)v;
}

// zero pad rows [N_NODES, N_PAD) of the stride-1024 f16 buffer (layers 2/3)
__global__ void k_zero_pad(_Float16* __restrict__ xh) {
    int idx = blockIdx.x * 256 + threadIdx.x;
    const int total = (N_PAD - N_NODES) * F;
    if (idx < total) xh[(size_t)N_NODES * F + idx] = (_Float16)0.f;
}

// W [K][1024] f32 -> W^T [1024][Kpad] f16 (transposed, zero-padded K)
__global__ void k_cvt_w(const float* __restrict__ W, _Float16* __restrict__ wh,
                        int K, int Kpad) {
    __shared__ float t[32][33];
    int kt = blockIdx.x * 32, nt = blockIdx.y * 32;
    int tx = threadIdx.x & 31, ty = threadIdx.x >> 5;
#pragma unroll
    for (int j = 0; j < 4; ++j) {
        int k = kt + ty + j * 8;
        t[ty + j * 8][tx] = (k < K) ? W[(size_t)k * F + nt + tx] : 0.f;
    }
    __syncthreads();
#pragma unroll
    for (int j = 0; j < 4; ++j) {
        int n = nt + ty + j * 8;
        wh[(size_t)n * Kpad + kt + tx] = (_Float16)t[tx][ty + j * 8];
    }
}

// ---------------- fused dual f16 MFMA GEMM ----------------
// fs = A@Ws + bs AND fd = A@Wd + bd in one pass (shared A tiles).
// A: [N_PAD][Kpad] f16 row-major. B*: W^T [1024][Kpad] f16.
// grid = (8, N_PAD/128), 256 threads. Single-pass f16 (mantissa 11b):
// predicted final absmax ~1e-2 < 3.27e-2 thr; fallback = 3-pass split-f16.
#define AS1C(p) ((const __attribute__((address_space(1))) void*)(p))
#define AS3(p)  ((__attribute__((address_space(3))) void*)(p))

__launch_bounds__(256, 3)
__global__ void k_gemm_dual(const _Float16* __restrict__ A,
                            const _Float16* __restrict__ Bs, const _Float16* __restrict__ Bd,
                            const float* __restrict__ bias_s, const float* __restrict__ bias_d,
                            float* __restrict__ Cs, float* __restrict__ Cd, int Kpad) {
    __shared__ _Float16 lds[12288];   // 3 tiles x [128][32] f16 = 24 KiB
    const int tid = threadIdx.x;
    const int l = tid & 63, w = tid >> 6;

    // XCD-aware bijective swizzle: nwg = 8*157 = 1256, 1256 % 8 == 0
    const int orig = blockIdx.y * 8 + blockIdx.x;
    const int wg = (orig & 7) * (N_PAD / 128) + (orig >> 3);
    const int by = wg >> 3, bx = wg & 7;

    // --- staging: wave w stages rows [w*32, w*32+32) of each tile, 2 calls/tile ---
    const int srow = w * 32 + (l >> 2);
    const int scol = (l & 3) * 8;
    const size_t aoff = (size_t)(by * 128 + srow) * Kpad + scol;
    const size_t boff = (size_t)(bx * 128 + srow) * Kpad + scol;
    const size_t step = (size_t)16 * Kpad;
    const _Float16* gA = A + aoff;
    const _Float16* gBs = Bs + boff;
    const _Float16* gBd = Bd + boff;

    _Float16* sA = lds + 0 * 4096 + w * 1024;
    _Float16* sBs = lds + 1 * 4096 + w * 1024;
    _Float16* sBd = lds + 2 * 4096 + w * 1024;

    // --- fragment coords: wave (wr,wc) owns a 64x64 sub-tile of each output ---
    const int wr = (w >> 1) * 64, wc = (w & 1) * 64;
    const int frow = l & 15;
    const int fko = (l >> 4) * 8;

    f32x4 accS[4][4], accD[4][4];
    const f32x4 fzero = {0.f, 0.f, 0.f, 0.f};
#pragma unroll
    for (int i = 0; i < 4; ++i)
#pragma unroll
        for (int j = 0; j < 4; ++j) { accS[i][j] = fzero; accD[i][j] = fzero; }

    for (int k0 = 0; k0 < Kpad; k0 += 32) {
        __builtin_amdgcn_global_load_lds(AS1C(gA + k0), AS3(sA), 16, 0, 0);
        __builtin_amdgcn_global_load_lds(AS1C(gA + step + k0), AS3(sA + 512), 16, 0, 0);
        __builtin_amdgcn_global_load_lds(AS1C(gBs + k0), AS3(sBs), 16, 0, 0);
        __builtin_amdgcn_global_load_lds(AS1C(gBs + step + k0), AS3(sBs + 512), 16, 0, 0);
        __builtin_amdgcn_global_load_lds(AS1C(gBd + k0), AS3(sBd), 16, 0, 0);
        __builtin_amdgcn_global_load_lds(AS1C(gBd + step + k0), AS3(sBd + 512), 16, 0, 0);
        __syncthreads();

        half8v a[4];
#pragma unroll
        for (int mi = 0; mi < 4; ++mi) {
            int ai = (wr + mi * 16 + frow) * 32 + fko;
            a[mi] = *(const half8v*)&lds[ai];
        }
#pragma unroll
        for (int ni = 0; ni < 4; ++ni) {
            int bi = (wc + ni * 16 + frow) * 32 + fko;
            half8v bs = *(const half8v*)&lds[4096 + bi];
            half8v bd = *(const half8v*)&lds[8192 + bi];
#pragma unroll
            for (int mi = 0; mi < 4; ++mi) {
                accS[mi][ni] = __builtin_amdgcn_mfma_f32_16x16x32_f16(a[mi], bs, accS[mi][ni], 0, 0, 0);
                accD[mi][ni] = __builtin_amdgcn_mfma_f32_16x16x32_f16(a[mi], bd, accD[mi][ni], 0, 0, 0);
            }
        }
        __syncthreads();
    }

    // epilogue: C/D layout col = lane&15, row = (lane>>4)*4 + reg
    const int crow0 = by * 128 + wr + (l >> 4) * 4;
    const int ccol = bx * 128 + wc + (l & 15);
#pragma unroll
    for (int mi = 0; mi < 4; ++mi) {
#pragma unroll
        for (int r = 0; r < 4; ++r) {
            int row = crow0 + mi * 16 + r;
            if (row < N_NODES) {
#pragma unroll
                for (int ni = 0; ni < 4; ++ni) {
                    int col = ccol + ni * 16;
                    Cs[(size_t)row * F + col] = accS[mi][ni][r] + bias_s[col];
                    Cd[(size_t)row * F + col] = accD[mi][ni][r] + bias_d[col];
                }
            }
        }
    }
}

// ---------------- fused GATv2 edge+softmax+aggregate (online softmax) ----------------
__launch_bounds__(256)
__global__ void k_gat(const float* __restrict__ fs, const float* __restrict__ fd,
                      const int* __restrict__ off, const int* __restrict__ csr_e,
                      const int* __restrict__ src, const float* __restrict__ attn,
                      const float* __restrict__ bias, float* __restrict__ y) {
    __shared__ int s_src[256];
    const int n = blockIdx.x;
    const int t = threadIdx.x;
    const int b = off[n], e = off[n + 1];

    const float4 fdv = *(const float4*)(fd + (size_t)n * F + t * 4);
    const float4 av = *(const float4*)(attn + (t >> 5) * 128 + (t & 31) * 4);

    float m = -1e30f, den = 0.f;
    float ax = 0.f, ay = 0.f, az = 0.f, aw = 0.f;

    for (int c0 = b; c0 < e; c0 += 256) {
        int ncur = e - c0; if (ncur > 256) ncur = 256;
        __syncthreads();
        if (t < ncur) s_src[t] = src[csr_e[c0 + t]];
        __syncthreads();
        for (int i = 0; i < ncur; ++i) {
            int s = s_src[i];
            const float4 fsv = *(const float4*)(fs + (size_t)s * F + t * 4);
            float vx = fsv.x + fdv.x; vx = vx > 0.f ? vx : 0.2f * vx;
            float vy = fsv.y + fdv.y; vy = vy > 0.f ? vy : 0.2f * vy;
            float vz = fsv.z + fdv.z; vz = vz > 0.f ? vz : 0.2f * vz;
            float vw = fsv.w + fdv.w; vw = vw > 0.f ? vw : 0.2f * vw;
            float p = vx * av.x + vy * av.y + vz * av.z + vw * av.w;
            p += __shfl_xor(p, 1);
            p += __shfl_xor(p, 2);
            p += __shfl_xor(p, 4);
            p += __shfl_xor(p, 8);
            p += __shfl_xor(p, 16);   // all 32 lanes of the head hold the score
            float mn = fmaxf(m, p);
            float so = __expf(m - mn);
            float wexp = __expf(p - mn);
            den = den * so + wexp;
            ax = ax * so + wexp * fsv.x;
            ay = ay * so + wexp * fsv.y;
            az = az * so + wexp * fsv.z;
            aw = aw * so + wexp * fsv.w;
            m = mn;
        }
    }
    float inv = (e > b) ? 1.f / den : 0.f;
    const float4 bb = *(const float4*)(bias + t * 4);
    float4 o;
    o.x = ax * inv + bb.x;
    o.y = ay * inv + bb.y;
    o.z = az * inv + bb.z;
    o.w = aw * inv + bb.w;
    *(float4*)(y + (size_t)n * F + t * 4) = o;
}

// ---------------- BatchNorm (2-stage deterministic) + lrelu + f16 emit ----------------
__global__ void k_bnpart(const float* __restrict__ y, float* __restrict__ part) {
    const int ROWS = (N_NODES + BN_CHUNKS - 1) / BN_CHUNKS;   // 79
    int blk = blockIdx.x;
    int t = threadIdx.x;
    int r0 = blk * ROWS;
    int r1 = r0 + ROWS; if (r1 > N_NODES) r1 = N_NODES;
    float sx = 0.f, sy = 0.f, sz = 0.f, sw = 0.f;
    float qx = 0.f, qy = 0.f, qz = 0.f, qw = 0.f;
    for (int r = r0; r < r1; ++r) {
        float4 v = *(const float4*)(y + (size_t)r * F + t * 4);
        sx += v.x; sy += v.y; sz += v.z; sw += v.w;
        qx += v.x * v.x; qy += v.y * v.y; qz += v.z * v.z; qw += v.w * v.w;
    }
    float4 s4; s4.x = sx; s4.y = sy; s4.z = sz; s4.w = sw;
    float4 q4; q4.x = qx; q4.y = qy; q4.z = qz; q4.w = qw;
    *(float4*)(part + (size_t)blk * (2 * F) + t * 4) = s4;
    *(float4*)(part + (size_t)blk * (2 * F) + F + t * 4) = q4;
}

__global__ void k_bnfin(const float* __restrict__ part, const float* __restrict__ gamma,
                        const float* __restrict__ beta, float* __restrict__ scale,
                        float* __restrict__ shift) {
    int c = blockIdx.x * blockDim.x + threadIdx.x;
    if (c >= F) return;
    float s = 0.f, q = 0.f;
    for (int b = 0; b < BN_CHUNKS; ++b) {
        s += part[(size_t)b * (2 * F) + c];
        q += part[(size_t)b * (2 * F) + F + c];
    }
    float mu = s / (float)N_NODES;
    float var = q / (float)N_NODES - mu * mu;
    float sc = gamma[c] * rsqrtf(var + BN_EPS);
    scale[c] = sc;
    shift[c] = beta[c] - mu * sc;
}

// in-place BN+lrelu on y; emits f16 copy for next layer's GEMM
__global__ void k_bnapply(const float* y, const float* __restrict__ scale,
                          const float* __restrict__ shift, float* x,
                          _Float16* __restrict__ xh) {
    int i = blockIdx.x * blockDim.x + threadIdx.x;
    if (i >= N_NODES * (F / 4)) return;
    int c4 = (i & (F / 4 - 1)) * 4;
    float4 v = ((const float4*)y)[i];
    float4 o;
    o.x = v.x * scale[c4 + 0] + shift[c4 + 0];
    o.y = v.y * scale[c4 + 1] + shift[c4 + 1];
    o.z = v.z * scale[c4 + 2] + shift[c4 + 2];
    o.w = v.w * scale[c4 + 3] + shift[c4 + 3];
    o.x = o.x > 0.f ? o.x : 0.01f * o.x;
    o.y = o.y > 0.f ? o.y : 0.01f * o.y;
    o.z = o.z > 0.f ? o.z : 0.01f * o.z;
    o.w = o.w > 0.f ? o.w : 0.01f * o.w;
    ((float4*)x)[i] = o;
    half4v h4;
    h4.x = (_Float16)o.x; h4.y = (_Float16)o.y;
    h4.z = (_Float16)o.z; h4.w = (_Float16)o.w;
    *(half4v*)&xh[(size_t)i * 4] = h4;
}

// ---------------- avg pool per graph (2D grid for parallelism) ----------------
__global__ void k_pool(const float* __restrict__ x, const int* __restrict__ gstart,
                       float* __restrict__ hg) {
    int g = blockIdx.y;
    int col = blockIdx.x * 256 + threadIdx.x;     // 4 x 256 covers F
    int r0 = gstart[g], r1 = gstart[g + 1];
    float s = 0.f;
    for (int r = r0; r < r1; ++r) s += x[(size_t)r * F + col];
    float inv = (r1 > r0) ? 1.f / (float)(r1 - r0) : 0.f;
    hg[(size_t)g * F + col] = s * inv;
}

// ---------------- small MLP GEMM (M=64 rows) ----------------
__global__ void k_mlp(const float* __restrict__ X, const float* __restrict__ W,
                      const float* __restrict__ b, float* __restrict__ out,
                      int K, int Nout, int act) {
    __shared__ float xs[1024];
    int row = blockIdx.y;
    int col = blockIdx.x * 256 + threadIdx.x;
    for (int k = threadIdx.x; k < K; k += 256) xs[k] = X[(size_t)row * K + k];
    __syncthreads();
    if (col < Nout) {
        float acc = b[col];
        for (int k = 0; k < K; ++k) acc += xs[k] * W[(size_t)k * Nout + col];
        if (act && acc < 0.f) acc *= 0.01f;
        out[(size_t)row * Nout + col] = acc;
    }
}

// ---------------- host orchestration ----------------
extern "C" void kernel_launch(void* const* d_in, const int* in_sizes, int n_in,
                              void* d_out, int out_size, void* d_ws, size_t ws_size,
                              hipStream_t stream) {
    const float* h = (const float*)d_in[0];
    const int* src = (const int*)d_in[1];
    const int* dst = (const int*)d_in[2];
    const int* gid = (const int*)d_in[3];

    const float *w_src[3], *b_src[3], *w_dst[3], *b_dst[3], *attn[3], *bias[3], *gamma[3], *beta[3];
    for (int l = 0; l < 3; ++l) {
        int base = 4 + l * 8;
        w_src[l] = (const float*)d_in[base + 0];
        b_src[l] = (const float*)d_in[base + 1];
        w_dst[l] = (const float*)d_in[base + 2];
        b_dst[l] = (const float*)d_in[base + 3];
        attn[l]  = (const float*)d_in[base + 4];
        bias[l]  = (const float*)d_in[base + 5];
        gamma[l] = (const float*)d_in[base + 6];
        beta[l]  = (const float*)d_in[base + 7];
    }
    const float* fc1_w = (const float*)d_in[28];
    const float* fc1_b = (const float*)d_in[29];
    const float* fc2_w = (const float*)d_in[30];
    const float* fc2_b = (const float*)d_in[31];
    const float* fc3_w = (const float*)d_in[32];
    const float* fc3_b = (const float*)d_in[33];

    // workspace carve
    char* base = (char*)d_ws;
    size_t o = 0;
    auto carve = [&](size_t bytes) -> char* {
        char* p = base + o;
        o += (bytes + 255) & ~(size_t)255;
        return p;
    };
    float* fs = (float*)carve((size_t)N_NODES * F * 4);
    float* fd = (float*)carve((size_t)N_NODES * F * 4);   // also y, also final x (in-place BN)
    _Float16* xh = (_Float16*)carve((size_t)N_PAD * F * 2);
    _Float16* wsh = (_Float16*)carve((size_t)F * F * 2);
    _Float16* wdh = (_Float16*)carve((size_t)F * F * 2);
    int* cnt = (int*)carve((size_t)N_NODES * 4);
    int* off = (int*)carve((size_t)(N_NODES + 1) * 4);
    int* cursor = (int*)carve((size_t)N_NODES * 4);
    int* csr_e = (int*)carve((size_t)N_EDGES * 4);
    float* part = (float*)carve((size_t)BN_CHUNKS * 2 * F * 4);
    float* scale = (float*)carve(F * 4);
    float* shift = (float*)carve(F * 4);
    int* gstart = (int*)carve((N_GRAPHS + 1) * 4);
    float* hg = (float*)carve((size_t)N_GRAPHS * F * 4);
    float* z1 = (float*)carve((size_t)N_GRAPHS * F * 4);
    float* z2 = (float*)carve((size_t)N_GRAPHS * F * 4);
    (void)ws_size;

    // ---- CSR build (deterministic: buckets sorted by edge id) ----
    k_zero_i32<<<(N_NODES + 255) / 256, 256, 0, stream>>>(cnt, N_NODES);
    k_count<<<(N_EDGES + 255) / 256, 256, 0, stream>>>(dst, cnt);
    k_scan<<<1, 256, 0, stream>>>(cnt, off);
    k_copy_i32<<<(N_NODES + 255) / 256, 256, 0, stream>>>(cursor, off, N_NODES);
    k_fill<<<(N_EDGES + 255) / 256, 256, 0, stream>>>(dst, cursor, csr_e);
    k_sort_buckets<<<(N_NODES + 255) / 256, 256, 0, stream>>>(off, csr_e);
    k_gstart<<<1, 128, 0, stream>>>(gid, gstart);

    // ---- input conversion + pad-row zeroing ----
    k_cvt_h<<<(N_PAD * 64 + 255) / 256, 256, 0, stream>>>(h, xh);
    k_zero_pad<<<((N_PAD - N_NODES) * F + 255) / 256, 256, 0, stream>>>(xh);

    // ---- 3 GATv2 + BN + lrelu layers ----
    const dim3 ggrid(8, N_PAD / 128);
    for (int l = 0; l < 3; ++l) {
        const int K = (l == 0) ? IN_F : F;
        const int Kp = (l == 0) ? 64 : F;
        k_cvt_w<<<dim3(Kp / 32, F / 32), 256, 0, stream>>>(w_src[l], wsh, K, Kp);
        k_cvt_w<<<dim3(Kp / 32, F / 32), 256, 0, stream>>>(w_dst[l], wdh, K, Kp);
        k_gemm_dual<<<ggrid, 256, 0, stream>>>(xh, wsh, wdh, b_src[l], b_dst[l], fs, fd, Kp);
        k_gat<<<N_NODES, 256, 0, stream>>>(fs, fd, off, csr_e, src, attn[l], bias[l], fd);
        k_bnpart<<<BN_CHUNKS, 256, 0, stream>>>(fd, part);
        k_bnfin<<<F / 256, 256, 0, stream>>>(part, gamma[l], beta[l], scale, shift);
        k_bnapply<<<(N_NODES * (F / 4) + 255) / 256, 256, 0, stream>>>(fd, scale, shift, fd, xh);
    }

    // ---- pool + MLP head ----
    k_pool<<<dim3(4, N_GRAPHS), 256, 0, stream>>>(fd, gstart, hg);
    k_mlp<<<dim3(4, N_GRAPHS), 256, 0, stream>>>(hg, fc1_w, fc1_b, z1, F, F, 1);
    k_mlp<<<dim3(4, N_GRAPHS), 256, 0, stream>>>(z1, fc2_w, fc2_b, z2, F, F, 1);
    k_mlp<<<dim3(1, N_GRAPHS), 256, 0, stream>>>(z2, fc3_w, fc3_b, (float*)d_out, F, NCLS, 0);
}

// Round 5
// 1020.294 us; speedup vs baseline: 3.5479x; 1.2101x over previous
//
#include <hip/hip_runtime.h>
#include <math.h>

#define N_NODES 20000
#define N_PAD   20096            // 157 * 128
#define N_EDGES 100000
#define N_GRAPHS 64
#define IN_F 63
#define NHEAD 8
#define F 1024                   // NHEAD * HID
#define NCLS 18
#define BN_EPS 1e-5f
#define BN_CHUNKS 256

typedef __attribute__((ext_vector_type(8))) _Float16 half8v;  // 8 f16 (4 VGPRs)
typedef __attribute__((ext_vector_type(4))) _Float16 half4v;
typedef __attribute__((ext_vector_type(4))) float f32x4;

// ---------------- utility kernels ----------------
__global__ void k_zero_i32(int* __restrict__ p, int n) {
    int i = blockIdx.x * blockDim.x + threadIdx.x;
    if (i < n) p[i] = 0;
}

__global__ void k_copy_i32(int* __restrict__ d, const int* __restrict__ s, int n) {
    int i = blockIdx.x * blockDim.x + threadIdx.x;
    if (i < n) d[i] = s[i];
}

// ---------------- CSR build over dst ----------------
__global__ void k_count(const int* __restrict__ dst, int* __restrict__ cnt) {
    int i = blockIdx.x * blockDim.x + threadIdx.x;
    if (i < N_EDGES) atomicAdd(&cnt[dst[i]], 1);
}

__global__ void k_scan(const int* __restrict__ cnt, int* __restrict__ off) {
    __shared__ int tsum[256];
    const int CH = (N_NODES + 255) / 256;
    int t = threadIdx.x;
    int s = 0;
    for (int i = 0; i < CH; ++i) {
        int idx = t * CH + i;
        if (idx < N_NODES) s += cnt[idx];
    }
    tsum[t] = s;
    __syncthreads();
    if (t == 0) {
        int acc = 0;
        for (int i = 0; i < 256; ++i) { int v = tsum[i]; tsum[i] = acc; acc += v; }
    }
    __syncthreads();
    int run = tsum[t];
    for (int i = 0; i < CH; ++i) {
        int idx = t * CH + i;
        if (idx < N_NODES) { off[idx] = run; run += cnt[idx]; }
    }
    if (t == 255) off[N_NODES] = run;
}

__global__ void k_fill(const int* __restrict__ dst, int* __restrict__ cursor,
                       int* __restrict__ csr_e) {
    int i = blockIdx.x * blockDim.x + threadIdx.x;
    if (i < N_EDGES) {
        int p = atomicAdd(&cursor[dst[i]], 1);
        csr_e[p] = i;
    }
}

__global__ void k_sort_buckets(const int* __restrict__ off, int* __restrict__ csr_e) {
    int n = blockIdx.x * blockDim.x + threadIdx.x;
    if (n >= N_NODES) return;
    int b = off[n], e = off[n + 1];
    for (int i = b + 1; i < e; ++i) {
        int v = csr_e[i];
        int j = i - 1;
        while (j >= b && csr_e[j] > v) { csr_e[j + 1] = csr_e[j]; --j; }
        csr_e[j + 1] = v;
    }
}

__global__ void k_gstart(const int* __restrict__ gid, int* __restrict__ gstart) {
    int g = blockIdx.x * blockDim.x + threadIdx.x;
    if (g > N_GRAPHS) return;
    int lo = 0, hi = N_NODES;
    while (lo < hi) {
        int mid = (lo + hi) >> 1;
        if (gid[mid] < g) lo = mid + 1; else hi = mid;
    }
    gstart[g] = lo;
}

// ---------------- conversions for f16 GEMM ----------------
__global__ void k_cvt_h(const float* __restrict__ h, _Float16* __restrict__ xh) {
    int idx = blockIdx.x * 256 + threadIdx.x;
    if (idx >= N_PAD * 64) return;
    int m = idx >> 6, k = idx & 63;
    float v = (m < N_NODES && k < IN_F) ? h[m * IN_F + k] : 0.f;
    xh[idx] = (_Float16)v;
}

__global__ void k_zero_pad(_Float16* __restrict__ xh) {
    int idx = blockIdx.x * 256 + threadIdx.x;
    const int total = (N_PAD - N_NODES) * F;
    if (idx < total) xh[(size_t)N_NODES * F + idx] = (_Float16)0.f;
}

// W [K][1024] f32 -> W^T [1024][Kpad] f16 (transposed, zero-padded K)
__global__ void k_cvt_w(const float* __restrict__ W, _Float16* __restrict__ wh,
                        int K, int Kpad) {
    __shared__ float t[32][33];
    int kt = blockIdx.x * 32, nt = blockIdx.y * 32;
    int tx = threadIdx.x & 31, ty = threadIdx.x >> 5;
#pragma unroll
    for (int j = 0; j < 4; ++j) {
        int k = kt + ty + j * 8;
        t[ty + j * 8][tx] = (k < K) ? W[(size_t)k * F + nt + tx] : 0.f;
    }
    __syncthreads();
#pragma unroll
    for (int j = 0; j < 4; ++j) {
        int n = nt + ty + j * 8;
        wh[(size_t)n * Kpad + kt + tx] = (_Float16)t[tx][ty + j * 8];
    }
}

// ---------------- fused dual f16 MFMA GEMM, BK=64, XOR-swizzled LDS ----------------
// fs16 = A@Ws + bs AND fd16 = A@Wd + bd (f16 outputs). Tiles [128 rows][64 halves]
// (128B rows). Swizzle (rule 21, both-sides): stage-time global chunk permutation
// chunk' = chunk ^ (row&7)  (per-lane constant ((l&7)^(l>>3))), read-time
// byte_in_row ^ ((row&7)<<4). LDS dest stays linear for global_load_lds.
#define AS1C(p) ((const __attribute__((address_space(1))) void*)(p))
#define AS3(p)  ((__attribute__((address_space(3))) void*)(p))

__launch_bounds__(256, 2)
__global__ void k_gemm_dual(const _Float16* __restrict__ A,
                            const _Float16* __restrict__ Bs, const _Float16* __restrict__ Bd,
                            const float* __restrict__ bias_s, const float* __restrict__ bias_d,
                            _Float16* __restrict__ Cs, _Float16* __restrict__ Cd, int Kpad) {
    __shared__ _Float16 lds[24576];   // 3 tiles x [128][64] f16 = 48 KiB
    const int tid = threadIdx.x;
    const int l = tid & 63, w = tid >> 6;

    // XCD-aware bijective swizzle: nwg = 8*157 = 1256, 1256 % 8 == 0
    const int orig = blockIdx.y * 8 + blockIdx.x;
    const int wg = (orig & 7) * (N_PAD / 128) + (orig >> 3);
    const int by = wg >> 3, bx = wg & 7;

    // --- staging: wave w stages rows [w*32, w*32+32), 4 loads x 8 rows per tile ---
    const int grow = w * 32 + (l >> 3);                 // global row within tile
    const int gcol = ((l & 7) ^ (l >> 3)) << 3;         // swizzled 16B chunk (halves)
    const size_t rstep = (size_t)8 * Kpad;              // 8 rows per load j
    const _Float16* gA = A + (size_t)(by * 128 + grow) * Kpad + gcol;
    const _Float16* gBs = Bs + (size_t)(bx * 128 + grow) * Kpad + gcol;
    const _Float16* gBd = Bd + (size_t)(bx * 128 + grow) * Kpad + gcol;
    char* sA = (char*)lds + w * 4096;                   // + j*1024, lane offset auto
    char* sBs = (char*)lds + 16384 + w * 4096;
    char* sBd = (char*)lds + 32768 + w * 4096;

    // --- fragment coords: wave (wr,wc) owns a 64x64 sub-tile of each output ---
    const int wr = (w >> 1) * 64, wc = (w & 1) * 64;
    const int frow = l & 15;
    const int swz = (l & 7) << 4;                       // read-side XOR (row&7 == l&7)
    const int kbase = (l >> 4) * 16;                    // byte offset of k-chunk

    f32x4 accS[4][4], accD[4][4];
    const f32x4 fzero = {0.f, 0.f, 0.f, 0.f};
#pragma unroll
    for (int i = 0; i < 4; ++i)
#pragma unroll
        for (int j = 0; j < 4; ++j) { accS[i][j] = fzero; accD[i][j] = fzero; }

    for (int k0 = 0; k0 < Kpad; k0 += 64) {
#pragma unroll
        for (int j = 0; j < 4; ++j) {
            __builtin_amdgcn_global_load_lds(AS1C(gA + j * rstep), AS3(sA + j * 1024), 16, 0, 0);
            __builtin_amdgcn_global_load_lds(AS1C(gBs + j * rstep), AS3(sBs + j * 1024), 16, 0, 0);
            __builtin_amdgcn_global_load_lds(AS1C(gBd + j * rstep), AS3(sBd + j * 1024), 16, 0, 0);
        }
        gA += 64; gBs += 64; gBd += 64;
        __syncthreads();

#pragma unroll
        for (int kk = 0; kk < 2; ++kk) {
            const int kb = (kk * 64 + kbase) ^ swz;     // swizzled byte within 128B row
            half8v a[4];
#pragma unroll
            for (int mi = 0; mi < 4; ++mi) {
                int row = wr + mi * 16 + frow;
                a[mi] = *(const half8v*)((const char*)lds + row * 128 + kb);
            }
#pragma unroll
            for (int ni = 0; ni < 4; ++ni) {
                int rowb = wc + ni * 16 + frow;
                half8v bs = *(const half8v*)((const char*)lds + 16384 + rowb * 128 + kb);
                half8v bd = *(const half8v*)((const char*)lds + 32768 + rowb * 128 + kb);
#pragma unroll
                for (int mi = 0; mi < 4; ++mi) {
                    accS[mi][ni] = __builtin_amdgcn_mfma_f32_16x16x32_f16(a[mi], bs, accS[mi][ni], 0, 0, 0);
                    accD[mi][ni] = __builtin_amdgcn_mfma_f32_16x16x32_f16(a[mi], bd, accD[mi][ni], 0, 0, 0);
                }
            }
        }
        __syncthreads();
    }

    // epilogue: C/D layout col = lane&15, row = (lane>>4)*4 + reg; f16 stores
    const int crow0 = by * 128 + wr + (l >> 4) * 4;
    const int ccol = bx * 128 + wc + (l & 15);
    float bS[4], bD[4];
#pragma unroll
    for (int ni = 0; ni < 4; ++ni) { bS[ni] = bias_s[ccol + ni * 16]; bD[ni] = bias_d[ccol + ni * 16]; }
#pragma unroll
    for (int mi = 0; mi < 4; ++mi) {
#pragma unroll
        for (int r = 0; r < 4; ++r) {
            int row = crow0 + mi * 16 + r;
            if (row < N_NODES) {
#pragma unroll
                for (int ni = 0; ni < 4; ++ni) {
                    int col = ccol + ni * 16;
                    Cs[(size_t)row * F + col] = (_Float16)(accS[mi][ni][r] + bS[ni]);
                    Cd[(size_t)row * F + col] = (_Float16)(accD[mi][ni][r] + bD[ni]);
                }
            }
        }
    }
}

// ---------------- fused GATv2 edge+softmax+aggregate (online softmax, f16 in) ----------------
__launch_bounds__(256)
__global__ void k_gat(const _Float16* __restrict__ fs, const _Float16* __restrict__ fd,
                      const int* __restrict__ off, const int* __restrict__ csr_e,
                      const int* __restrict__ src, const float* __restrict__ attn,
                      const float* __restrict__ bias, float* __restrict__ y) {
    __shared__ int s_src[256];
    const int n = blockIdx.x;
    const int t = threadIdx.x;
    const int b = off[n], e = off[n + 1];

    half4v fdv = *(const half4v*)(fd + (size_t)n * F + t * 4);
    const float fd0 = (float)fdv.x, fd1 = (float)fdv.y, fd2 = (float)fdv.z, fd3 = (float)fdv.w;
    const float4 av = *(const float4*)(attn + (t >> 5) * 128 + (t & 31) * 4);

    float m = -1e30f, den = 0.f;
    float ax = 0.f, ay = 0.f, az = 0.f, aw = 0.f;

    for (int c0 = b; c0 < e; c0 += 256) {
        int ncur = e - c0; if (ncur > 256) ncur = 256;
        __syncthreads();
        if (t < ncur) s_src[t] = src[csr_e[c0 + t]];
        __syncthreads();
        for (int i = 0; i < ncur; ++i) {
            int s = s_src[i];
            half4v fsv = *(const half4v*)(fs + (size_t)s * F + t * 4);
            float f0 = (float)fsv.x, f1 = (float)fsv.y, f2 = (float)fsv.z, f3 = (float)fsv.w;
            float vx = f0 + fd0; vx = vx > 0.f ? vx : 0.2f * vx;
            float vy = f1 + fd1; vy = vy > 0.f ? vy : 0.2f * vy;
            float vz = f2 + fd2; vz = vz > 0.f ? vz : 0.2f * vz;
            float vw = f3 + fd3; vw = vw > 0.f ? vw : 0.2f * vw;
            float p = vx * av.x + vy * av.y + vz * av.z + vw * av.w;
            p += __shfl_xor(p, 1);
            p += __shfl_xor(p, 2);
            p += __shfl_xor(p, 4);
            p += __shfl_xor(p, 8);
            p += __shfl_xor(p, 16);   // all 32 lanes of the head hold the score
            float mn = fmaxf(m, p);
            float so = __expf(m - mn);
            float wexp = __expf(p - mn);
            den = den * so + wexp;
            ax = ax * so + wexp * f0;
            ay = ay * so + wexp * f1;
            az = az * so + wexp * f2;
            aw = aw * so + wexp * f3;
            m = mn;
        }
    }
    float inv = (e > b) ? 1.f / den : 0.f;
    const float4 bb = *(const float4*)(bias + t * 4);
    float4 o;
    o.x = ax * inv + bb.x;
    o.y = ay * inv + bb.y;
    o.z = az * inv + bb.z;
    o.w = aw * inv + bb.w;
    *(float4*)(y + (size_t)n * F + t * 4) = o;
}

// ---------------- BatchNorm (2-stage deterministic) + lrelu ----------------
__global__ void k_bnpart(const float* __restrict__ y, float* __restrict__ part) {
    const int ROWS = (N_NODES + BN_CHUNKS - 1) / BN_CHUNKS;
    int blk = blockIdx.x;
    int t = threadIdx.x;
    int r0 = blk * ROWS;
    int r1 = r0 + ROWS; if (r1 > N_NODES) r1 = N_NODES;
    float sx = 0.f, sy = 0.f, sz = 0.f, sw = 0.f;
    float qx = 0.f, qy = 0.f, qz = 0.f, qw = 0.f;
    for (int r = r0; r < r1; ++r) {
        float4 v = *(const float4*)(y + (size_t)r * F + t * 4);
        sx += v.x; sy += v.y; sz += v.z; sw += v.w;
        qx += v.x * v.x; qy += v.y * v.y; qz += v.z * v.z; qw += v.w * v.w;
    }
    float4 s4; s4.x = sx; s4.y = sy; s4.z = sz; s4.w = sw;
    float4 q4; q4.x = qx; q4.y = qy; q4.z = qz; q4.w = qw;
    *(float4*)(part + (size_t)blk * (2 * F) + t * 4) = s4;
    *(float4*)(part + (size_t)blk * (2 * F) + F + t * 4) = q4;
}

__global__ void k_bnfin(const float* __restrict__ part, const float* __restrict__ gamma,
                        const float* __restrict__ beta, float* __restrict__ scale,
                        float* __restrict__ shift) {
    int c = blockIdx.x * blockDim.x + threadIdx.x;
    if (c >= F) return;
    float s = 0.f, q = 0.f;
    for (int b = 0; b < BN_CHUNKS; ++b) {
        s += part[(size_t)b * (2 * F) + c];
        q += part[(size_t)b * (2 * F) + F + c];
    }
    float mu = s / (float)N_NODES;
    float var = q / (float)N_NODES - mu * mu;
    float sc = gamma[c] * rsqrtf(var + BN_EPS);
    scale[c] = sc;
    shift[c] = beta[c] - mu * sc;
}

// BN+lrelu; mode 0: emit f16 xh only (layers 1,2); mode 1: emit f32 x only (layer 3)
__global__ void k_bnapply(const float* __restrict__ y, const float* __restrict__ scale,
                          const float* __restrict__ shift, float* __restrict__ x,
                          _Float16* __restrict__ xh, int mode) {
    int i = blockIdx.x * blockDim.x + threadIdx.x;
    if (i >= N_NODES * (F / 4)) return;
    int c4 = (i & (F / 4 - 1)) * 4;
    float4 v = ((const float4*)y)[i];
    float4 o;
    o.x = v.x * scale[c4 + 0] + shift[c4 + 0];
    o.y = v.y * scale[c4 + 1] + shift[c4 + 1];
    o.z = v.z * scale[c4 + 2] + shift[c4 + 2];
    o.w = v.w * scale[c4 + 3] + shift[c4 + 3];
    o.x = o.x > 0.f ? o.x : 0.01f * o.x;
    o.y = o.y > 0.f ? o.y : 0.01f * o.y;
    o.z = o.z > 0.f ? o.z : 0.01f * o.z;
    o.w = o.w > 0.f ? o.w : 0.01f * o.w;
    if (mode == 0) {
        half4v h4;
        h4.x = (_Float16)o.x; h4.y = (_Float16)o.y;
        h4.z = (_Float16)o.z; h4.w = (_Float16)o.w;
        *(half4v*)&xh[(size_t)i * 4] = h4;
    } else {
        ((float4*)x)[i] = o;
    }
}

// ---------------- avg pool per graph (2D grid) ----------------
__global__ void k_pool(const float* __restrict__ x, const int* __restrict__ gstart,
                       float* __restrict__ hg) {
    int g = blockIdx.y;
    int col = blockIdx.x * 256 + threadIdx.x;
    int r0 = gstart[g], r1 = gstart[g + 1];
    float s = 0.f;
    for (int r = r0; r < r1; ++r) s += x[(size_t)r * F + col];
    float inv = (r1 > r0) ? 1.f / (float)(r1 - r0) : 0.f;
    hg[(size_t)g * F + col] = s * inv;
}

// ---------------- small MLP GEMM (M=64 rows) ----------------
__global__ void k_mlp(const float* __restrict__ X, const float* __restrict__ W,
                      const float* __restrict__ b, float* __restrict__ out,
                      int K, int Nout, int act) {
    __shared__ float xs[1024];
    int row = blockIdx.y;
    int col = blockIdx.x * 256 + threadIdx.x;
    for (int k = threadIdx.x; k < K; k += 256) xs[k] = X[(size_t)row * K + k];
    __syncthreads();
    if (col < Nout) {
        float acc = b[col];
        for (int k = 0; k < K; ++k) acc += xs[k] * W[(size_t)k * Nout + col];
        if (act && acc < 0.f) acc *= 0.01f;
        out[(size_t)row * Nout + col] = acc;
    }
}

// ---------------- host orchestration ----------------
extern "C" void kernel_launch(void* const* d_in, const int* in_sizes, int n_in,
                              void* d_out, int out_size, void* d_ws, size_t ws_size,
                              hipStream_t stream) {
    const float* h = (const float*)d_in[0];
    const int* src = (const int*)d_in[1];
    const int* dst = (const int*)d_in[2];
    const int* gid = (const int*)d_in[3];

    const float *w_src[3], *b_src[3], *w_dst[3], *b_dst[3], *attn[3], *bias[3], *gamma[3], *beta[3];
    for (int l = 0; l < 3; ++l) {
        int base = 4 + l * 8;
        w_src[l] = (const float*)d_in[base + 0];
        b_src[l] = (const float*)d_in[base + 1];
        w_dst[l] = (const float*)d_in[base + 2];
        b_dst[l] = (const float*)d_in[base + 3];
        attn[l]  = (const float*)d_in[base + 4];
        bias[l]  = (const float*)d_in[base + 5];
        gamma[l] = (const float*)d_in[base + 6];
        beta[l]  = (const float*)d_in[base + 7];
    }
    const float* fc1_w = (const float*)d_in[28];
    const float* fc1_b = (const float*)d_in[29];
    const float* fc2_w = (const float*)d_in[30];
    const float* fc2_b = (const float*)d_in[31];
    const float* fc3_w = (const float*)d_in[32];
    const float* fc3_b = (const float*)d_in[33];

    // workspace carve
    char* base = (char*)d_ws;
    size_t o = 0;
    auto carve = [&](size_t bytes) -> char* {
        char* p = base + o;
        o += (bytes + 255) & ~(size_t)255;
        return p;
    };
    _Float16* fs16 = (_Float16*)carve((size_t)N_NODES * F * 2);
    _Float16* fd16 = (_Float16*)carve((size_t)N_NODES * F * 2);
    float* y = (float*)carve((size_t)N_NODES * F * 4);
    _Float16* xh = (_Float16*)carve((size_t)N_PAD * F * 2);
    _Float16* wsh = (_Float16*)carve((size_t)F * F * 2);
    _Float16* wdh = (_Float16*)carve((size_t)F * F * 2);
    int* cnt = (int*)carve((size_t)N_NODES * 4);
    int* off = (int*)carve((size_t)(N_NODES + 1) * 4);
    int* cursor = (int*)carve((size_t)N_NODES * 4);
    int* csr_e = (int*)carve((size_t)N_EDGES * 4);
    float* part = (float*)carve((size_t)BN_CHUNKS * 2 * F * 4);
    float* scale = (float*)carve(F * 4);
    float* shift = (float*)carve(F * 4);
    int* gstart = (int*)carve((N_GRAPHS + 1) * 4);
    float* hg = (float*)carve((size_t)N_GRAPHS * F * 4);
    float* z1 = (float*)carve((size_t)N_GRAPHS * F * 4);
    float* z2 = (float*)carve((size_t)N_GRAPHS * F * 4);
    (void)ws_size;

    // ---- CSR build (deterministic: buckets sorted by edge id) ----
    k_zero_i32<<<(N_NODES + 255) / 256, 256, 0, stream>>>(cnt, N_NODES);
    k_count<<<(N_EDGES + 255) / 256, 256, 0, stream>>>(dst, cnt);
    k_scan<<<1, 256, 0, stream>>>(cnt, off);
    k_copy_i32<<<(N_NODES + 255) / 256, 256, 0, stream>>>(cursor, off, N_NODES);
    k_fill<<<(N_EDGES + 255) / 256, 256, 0, stream>>>(dst, cursor, csr_e);
    k_sort_buckets<<<(N_NODES + 255) / 256, 256, 0, stream>>>(off, csr_e);
    k_gstart<<<1, 128, 0, stream>>>(gid, gstart);

    // ---- input conversion + pad-row zeroing ----
    k_cvt_h<<<(N_PAD * 64 + 255) / 256, 256, 0, stream>>>(h, xh);
    k_zero_pad<<<((N_PAD - N_NODES) * F + 255) / 256, 256, 0, stream>>>(xh);

    // ---- 3 GATv2 + BN + lrelu layers ----
    const dim3 ggrid(8, N_PAD / 128);
    for (int l = 0; l < 3; ++l) {
        const int K = (l == 0) ? IN_F : F;
        const int Kp = (l == 0) ? 64 : F;
        k_cvt_w<<<dim3(Kp / 32, F / 32), 256, 0, stream>>>(w_src[l], wsh, K, Kp);
        k_cvt_w<<<dim3(Kp / 32, F / 32), 256, 0, stream>>>(w_dst[l], wdh, K, Kp);
        k_gemm_dual<<<ggrid, 256, 0, stream>>>(xh, wsh, wdh, b_src[l], b_dst[l], fs16, fd16, Kp);
        k_gat<<<N_NODES, 256, 0, stream>>>(fs16, fd16, off, csr_e, src, attn[l], bias[l], y);
        k_bnpart<<<BN_CHUNKS, 256, 0, stream>>>(y, part);
        k_bnfin<<<F / 256, 256, 0, stream>>>(part, gamma[l], beta[l], scale, shift);
        k_bnapply<<<(N_NODES * (F / 4) + 255) / 256, 256, 0, stream>>>(
            y, scale, shift, y, xh, (l == 2) ? 1 : 0);
    }

    // ---- pool + MLP head ----
    k_pool<<<dim3(4, N_GRAPHS), 256, 0, stream>>>(y, gstart, hg);
    k_mlp<<<dim3(4, N_GRAPHS), 256, 0, stream>>>(hg, fc1_w, fc1_b, z1, F, F, 1);
    k_mlp<<<dim3(4, N_GRAPHS), 256, 0, stream>>>(z1, fc2_w, fc2_b, z2, F, F, 1);
    k_mlp<<<dim3(1, N_GRAPHS), 256, 0, stream>>>(z2, fc3_w, fc3_b, (float*)d_out, F, NCLS, 0);
}

// Round 6
// 851.022 us; speedup vs baseline: 4.2536x; 1.1989x over previous
//
#include <hip/hip_runtime.h>
#include <math.h>

#define N_NODES 20000
#define N_PAD   20096            // 157 * 128
#define N_EDGES 100000
#define N_GRAPHS 64
#define IN_F 63
#define NHEAD 8
#define F 1024                   // NHEAD * HID
#define NCLS 18
#define BN_EPS 1e-5f
#define BN_CHUNKS 256

typedef __attribute__((ext_vector_type(8))) _Float16 half8v;  // 8 f16 (4 VGPRs)
typedef __attribute__((ext_vector_type(4))) _Float16 half4v;
typedef __attribute__((ext_vector_type(4))) float f32x4;

// ---------------- utility kernels ----------------
__global__ void k_zero_i32(int* __restrict__ p, int n) {
    int i = blockIdx.x * blockDim.x + threadIdx.x;
    if (i < n) p[i] = 0;
}

__global__ void k_copy_i32(int* __restrict__ d, const int* __restrict__ s, int n) {
    int i = blockIdx.x * blockDim.x + threadIdx.x;
    if (i < n) d[i] = s[i];
}

// ---------------- CSR build over dst ----------------
__global__ void k_count(const int* __restrict__ dst, int* __restrict__ cnt) {
    int i = blockIdx.x * blockDim.x + threadIdx.x;
    if (i < N_EDGES) atomicAdd(&cnt[dst[i]], 1);
}

__global__ void k_scan(const int* __restrict__ cnt, int* __restrict__ off) {
    __shared__ int tsum[256];
    const int CH = (N_NODES + 255) / 256;
    int t = threadIdx.x;
    int s = 0;
    for (int i = 0; i < CH; ++i) {
        int idx = t * CH + i;
        if (idx < N_NODES) s += cnt[idx];
    }
    tsum[t] = s;
    __syncthreads();
    if (t == 0) {
        int acc = 0;
        for (int i = 0; i < 256; ++i) { int v = tsum[i]; tsum[i] = acc; acc += v; }
    }
    __syncthreads();
    int run = tsum[t];
    for (int i = 0; i < CH; ++i) {
        int idx = t * CH + i;
        if (idx < N_NODES) { off[idx] = run; run += cnt[idx]; }
    }
    if (t == 255) off[N_NODES] = run;
}

__global__ void k_fill(const int* __restrict__ dst, int* __restrict__ cursor,
                       int* __restrict__ csr_e) {
    int i = blockIdx.x * blockDim.x + threadIdx.x;
    if (i < N_EDGES) {
        int p = atomicAdd(&cursor[dst[i]], 1);
        csr_e[p] = i;
    }
}

__global__ void k_sort_buckets(const int* __restrict__ off, int* __restrict__ csr_e) {
    int n = blockIdx.x * blockDim.x + threadIdx.x;
    if (n >= N_NODES) return;
    int b = off[n], e = off[n + 1];
    for (int i = b + 1; i < e; ++i) {
        int v = csr_e[i];
        int j = i - 1;
        while (j >= b && csr_e[j] > v) { csr_e[j + 1] = csr_e[j]; --j; }
        csr_e[j + 1] = v;
    }
}

__global__ void k_gstart(const int* __restrict__ gid, int* __restrict__ gstart) {
    int g = blockIdx.x * blockDim.x + threadIdx.x;
    if (g > N_GRAPHS) return;
    int lo = 0, hi = N_NODES;
    while (lo < hi) {
        int mid = (lo + hi) >> 1;
        if (gid[mid] < g) lo = mid + 1; else hi = mid;
    }
    gstart[g] = lo;
}

// ---------------- conversions for f16 GEMM ----------------
__global__ void k_cvt_h(const float* __restrict__ h, _Float16* __restrict__ xh) {
    int idx = blockIdx.x * 256 + threadIdx.x;
    if (idx >= N_PAD * 64) return;
    int m = idx >> 6, k = idx & 63;
    float v = (m < N_NODES && k < IN_F) ? h[m * IN_F + k] : 0.f;
    xh[idx] = (_Float16)v;
}

__global__ void k_zero_pad(_Float16* __restrict__ xh) {
    int idx = blockIdx.x * 256 + threadIdx.x;
    const int total = (N_PAD - N_NODES) * F;
    if (idx < total) xh[(size_t)N_NODES * F + idx] = (_Float16)0.f;
}

// W [K][1024] f32 -> W^T [1024][Kpad] f16 (transposed, zero-padded K)
__global__ void k_cvt_w(const float* __restrict__ W, _Float16* __restrict__ wh,
                        int K, int Kpad) {
    __shared__ float t[32][33];
    int kt = blockIdx.x * 32, nt = blockIdx.y * 32;
    int tx = threadIdx.x & 31, ty = threadIdx.x >> 5;
#pragma unroll
    for (int j = 0; j < 4; ++j) {
        int k = kt + ty + j * 8;
        t[ty + j * 8][tx] = (k < K) ? W[(size_t)k * F + nt + tx] : 0.f;
    }
    __syncthreads();
#pragma unroll
    for (int j = 0; j < 4; ++j) {
        int n = nt + ty + j * 8;
        wh[(size_t)n * Kpad + kt + tx] = (_Float16)t[tx][ty + j * 8];
    }
}

// ---------------- fused dual f16 MFMA GEMM, BK=64, XOR-swizzled LDS ----------------
#define AS1C(p) ((const __attribute__((address_space(1))) void*)(p))
#define AS3(p)  ((__attribute__((address_space(3))) void*)(p))

__launch_bounds__(256, 2)
__global__ void k_gemm_dual(const _Float16* __restrict__ A,
                            const _Float16* __restrict__ Bs, const _Float16* __restrict__ Bd,
                            const float* __restrict__ bias_s, const float* __restrict__ bias_d,
                            _Float16* __restrict__ Cs, _Float16* __restrict__ Cd, int Kpad) {
    __shared__ _Float16 lds[24576];   // 3 tiles x [128][64] f16 = 48 KiB
    const int tid = threadIdx.x;
    const int l = tid & 63, w = tid >> 6;

    // XCD-aware bijective swizzle: nwg = 8*157 = 1256, 1256 % 8 == 0
    const int orig = blockIdx.y * 8 + blockIdx.x;
    const int wg = (orig & 7) * (N_PAD / 128) + (orig >> 3);
    const int by = wg >> 3, bx = wg & 7;

    // --- staging: wave w stages rows [w*32, w*32+32), 4 loads x 8 rows per tile ---
    const int grow = w * 32 + (l >> 3);
    const int gcol = ((l & 7) ^ (l >> 3)) << 3;         // swizzled 16B chunk (halves)
    const size_t rstep = (size_t)8 * Kpad;
    const _Float16* gA = A + (size_t)(by * 128 + grow) * Kpad + gcol;
    const _Float16* gBs = Bs + (size_t)(bx * 128 + grow) * Kpad + gcol;
    const _Float16* gBd = Bd + (size_t)(bx * 128 + grow) * Kpad + gcol;
    char* sA = (char*)lds + w * 4096;
    char* sBs = (char*)lds + 16384 + w * 4096;
    char* sBd = (char*)lds + 32768 + w * 4096;

    // --- fragment coords: wave (wr,wc) owns a 64x64 sub-tile of each output ---
    const int wr = (w >> 1) * 64, wc = (w & 1) * 64;
    const int frow = l & 15;
    const int swz = (l & 7) << 4;                       // read-side XOR (row&7 == l&7)
    const int kbase = (l >> 4) * 16;

    f32x4 accS[4][4], accD[4][4];
    const f32x4 fzero = {0.f, 0.f, 0.f, 0.f};
#pragma unroll
    for (int i = 0; i < 4; ++i)
#pragma unroll
        for (int j = 0; j < 4; ++j) { accS[i][j] = fzero; accD[i][j] = fzero; }

    for (int k0 = 0; k0 < Kpad; k0 += 64) {
#pragma unroll
        for (int j = 0; j < 4; ++j) {
            __builtin_amdgcn_global_load_lds(AS1C(gA + j * rstep), AS3(sA + j * 1024), 16, 0, 0);
            __builtin_amdgcn_global_load_lds(AS1C(gBs + j * rstep), AS3(sBs + j * 1024), 16, 0, 0);
            __builtin_amdgcn_global_load_lds(AS1C(gBd + j * rstep), AS3(sBd + j * 1024), 16, 0, 0);
        }
        gA += 64; gBs += 64; gBd += 64;
        __syncthreads();

#pragma unroll
        for (int kk = 0; kk < 2; ++kk) {
            const int kb = (kk * 64 + kbase) ^ swz;
            half8v a[4];
#pragma unroll
            for (int mi = 0; mi < 4; ++mi) {
                int row = wr + mi * 16 + frow;
                a[mi] = *(const half8v*)((const char*)lds + row * 128 + kb);
            }
#pragma unroll
            for (int ni = 0; ni < 4; ++ni) {
                int rowb = wc + ni * 16 + frow;
                half8v bs = *(const half8v*)((const char*)lds + 16384 + rowb * 128 + kb);
                half8v bd = *(const half8v*)((const char*)lds + 32768 + rowb * 128 + kb);
#pragma unroll
                for (int mi = 0; mi < 4; ++mi) {
                    accS[mi][ni] = __builtin_amdgcn_mfma_f32_16x16x32_f16(a[mi], bs, accS[mi][ni], 0, 0, 0);
                    accD[mi][ni] = __builtin_amdgcn_mfma_f32_16x16x32_f16(a[mi], bd, accD[mi][ni], 0, 0, 0);
                }
            }
        }
        __syncthreads();
    }

    // epilogue: C/D layout col = lane&15, row = (lane>>4)*4 + reg; f16 stores
    const int crow0 = by * 128 + wr + (l >> 4) * 4;
    const int ccol = bx * 128 + wc + (l & 15);
    float bS[4], bD[4];
#pragma unroll
    for (int ni = 0; ni < 4; ++ni) { bS[ni] = bias_s[ccol + ni * 16]; bD[ni] = bias_d[ccol + ni * 16]; }
#pragma unroll
    for (int mi = 0; mi < 4; ++mi) {
#pragma unroll
        for (int r = 0; r < 4; ++r) {
            int row = crow0 + mi * 16 + r;
            if (row < N_NODES) {
#pragma unroll
                for (int ni = 0; ni < 4; ++ni) {
                    int col = ccol + ni * 16;
                    Cs[(size_t)row * F + col] = (_Float16)(accS[mi][ni][r] + bS[ni]);
                    Cd[(size_t)row * F + col] = (_Float16)(accD[mi][ni][r] + bD[ni]);
                }
            }
        }
    }
}

// ---------------- fused GATv2 edge+softmax+aggregate (online softmax, f16 in) ----------------
__launch_bounds__(256)
__global__ void k_gat(const _Float16* __restrict__ fs, const _Float16* __restrict__ fd,
                      const int* __restrict__ off, const int* __restrict__ csr_e,
                      const int* __restrict__ src, const float* __restrict__ attn,
                      const float* __restrict__ bias, float* __restrict__ y) {
    __shared__ int s_src[256];
    const int n = blockIdx.x;
    const int t = threadIdx.x;
    const int b = off[n], e = off[n + 1];

    half4v fdv = *(const half4v*)(fd + (size_t)n * F + t * 4);
    const float fd0 = (float)fdv.x, fd1 = (float)fdv.y, fd2 = (float)fdv.z, fd3 = (float)fdv.w;
    const float4 av = *(const float4*)(attn + (t >> 5) * 128 + (t & 31) * 4);

    float m = -1e30f, den = 0.f;
    float ax = 0.f, ay = 0.f, az = 0.f, aw = 0.f;

    for (int c0 = b; c0 < e; c0 += 256) {
        int ncur = e - c0; if (ncur > 256) ncur = 256;
        __syncthreads();
        if (t < ncur) s_src[t] = src[csr_e[c0 + t]];
        __syncthreads();
        for (int i = 0; i < ncur; ++i) {
            int s = s_src[i];
            half4v fsv = *(const half4v*)(fs + (size_t)s * F + t * 4);
            float f0 = (float)fsv.x, f1 = (float)fsv.y, f2 = (float)fsv.z, f3 = (float)fsv.w;
            float vx = f0 + fd0; vx = vx > 0.f ? vx : 0.2f * vx;
            float vy = f1 + fd1; vy = vy > 0.f ? vy : 0.2f * vy;
            float vz = f2 + fd2; vz = vz > 0.f ? vz : 0.2f * vz;
            float vw = f3 + fd3; vw = vw > 0.f ? vw : 0.2f * vw;
            float p = vx * av.x + vy * av.y + vz * av.z + vw * av.w;
            p += __shfl_xor(p, 1);
            p += __shfl_xor(p, 2);
            p += __shfl_xor(p, 4);
            p += __shfl_xor(p, 8);
            p += __shfl_xor(p, 16);
            float mn = fmaxf(m, p);
            float so = __expf(m - mn);
            float wexp = __expf(p - mn);
            den = den * so + wexp;
            ax = ax * so + wexp * f0;
            ay = ay * so + wexp * f1;
            az = az * so + wexp * f2;
            aw = aw * so + wexp * f3;
            m = mn;
        }
    }
    float inv = (e > b) ? 1.f / den : 0.f;
    const float4 bb = *(const float4*)(bias + t * 4);
    float4 o;
    o.x = ax * inv + bb.x;
    o.y = ay * inv + bb.y;
    o.z = az * inv + bb.z;
    o.w = aw * inv + bb.w;
    *(float4*)(y + (size_t)n * F + t * 4) = o;
}

// ---------------- BatchNorm (2-stage deterministic) + lrelu ----------------
__global__ void k_bnpart(const float* __restrict__ y, float* __restrict__ part) {
    const int ROWS = (N_NODES + BN_CHUNKS - 1) / BN_CHUNKS;
    int blk = blockIdx.x;
    int t = threadIdx.x;
    int r0 = blk * ROWS;
    int r1 = r0 + ROWS; if (r1 > N_NODES) r1 = N_NODES;
    float sx = 0.f, sy = 0.f, sz = 0.f, sw = 0.f;
    float qx = 0.f, qy = 0.f, qz = 0.f, qw = 0.f;
    for (int r = r0; r < r1; ++r) {
        float4 v = *(const float4*)(y + (size_t)r * F + t * 4);
        sx += v.x; sy += v.y; sz += v.z; sw += v.w;
        qx += v.x * v.x; qy += v.y * v.y; qz += v.z * v.z; qw += v.w * v.w;
    }
    float4 s4; s4.x = sx; s4.y = sy; s4.z = sz; s4.w = sw;
    float4 q4; q4.x = qx; q4.y = qy; q4.z = qz; q4.w = qw;
    *(float4*)(part + (size_t)blk * (2 * F) + t * 4) = s4;
    *(float4*)(part + (size_t)blk * (2 * F) + F + t * 4) = q4;
}

__global__ void k_bnfin(const float* __restrict__ part, const float* __restrict__ gamma,
                        const float* __restrict__ beta, float* __restrict__ scale,
                        float* __restrict__ shift) {
    int c = blockIdx.x * blockDim.x + threadIdx.x;
    if (c >= F) return;
    float s = 0.f, q = 0.f;
    for (int b = 0; b < BN_CHUNKS; ++b) {
        s += part[(size_t)b * (2 * F) + c];
        q += part[(size_t)b * (2 * F) + F + c];
    }
    float mu = s / (float)N_NODES;
    float var = q / (float)N_NODES - mu * mu;
    float sc = gamma[c] * rsqrtf(var + BN_EPS);
    scale[c] = sc;
    shift[c] = beta[c] - mu * sc;
}

// BN+lrelu; mode 0: emit f16 xh only (layers 1,2); mode 1: emit f32 x only (layer 3)
__global__ void k_bnapply(const float* __restrict__ y, const float* __restrict__ scale,
                          const float* __restrict__ shift, float* __restrict__ x,
                          _Float16* __restrict__ xh, int mode) {
    int i = blockIdx.x * blockDim.x + threadIdx.x;
    if (i >= N_NODES * (F / 4)) return;
    int c4 = (i & (F / 4 - 1)) * 4;
    float4 v = ((const float4*)y)[i];
    float4 o;
    o.x = v.x * scale[c4 + 0] + shift[c4 + 0];
    o.y = v.y * scale[c4 + 1] + shift[c4 + 1];
    o.z = v.z * scale[c4 + 2] + shift[c4 + 2];
    o.w = v.w * scale[c4 + 3] + shift[c4 + 3];
    o.x = o.x > 0.f ? o.x : 0.01f * o.x;
    o.y = o.y > 0.f ? o.y : 0.01f * o.y;
    o.z = o.z > 0.f ? o.z : 0.01f * o.z;
    o.w = o.w > 0.f ? o.w : 0.01f * o.w;
    if (mode == 0) {
        half4v h4;
        h4.x = (_Float16)o.x; h4.y = (_Float16)o.y;
        h4.z = (_Float16)o.z; h4.w = (_Float16)o.w;
        *(half4v*)&xh[(size_t)i * 4] = h4;
    } else {
        ((float4*)x)[i] = o;
    }
}

// ---------------- avg pool per graph -> f16 (input to fc1 MFMA) ----------------
__global__ void k_pool(const float* __restrict__ x, const int* __restrict__ gstart,
                       _Float16* __restrict__ hg16) {
    int g = blockIdx.y;
    int col = blockIdx.x * 256 + threadIdx.x;
    int r0 = gstart[g], r1 = gstart[g + 1];
    float s = 0.f;
    for (int r = r0; r < r1; ++r) s += x[(size_t)r * F + col];
    float inv = (r1 > r0) ? 1.f / (float)(r1 - r0) : 0.f;
    hg16[(size_t)g * F + col] = (_Float16)(s * inv);
}

// ---------------- MLP fc1/fc2: f16 MFMA GEMM, M=64, N=K=1024 ----------------
// A16 [64][1024] f16, Bt [1024][1024] f16 (W^T). grid = 16 blocks (64-col tiles),
// 256 thr = 4 waves; wave w computes rows [16w,16w+16) x 64 cols. lrelu 0.01.
// mode 0: write out16 f16; mode 1: write out32 f32.
__launch_bounds__(256)
__global__ void k_mlp_mfma(const _Float16* __restrict__ A16, const _Float16* __restrict__ Bt,
                           const float* __restrict__ bias, _Float16* __restrict__ out16,
                           float* __restrict__ out32, int mode) {
    const int l = threadIdx.x & 63, w = threadIdx.x >> 6;
    const int bx = blockIdx.x;
    const int fko = (l >> 4) * 8;

    const _Float16* pa = A16 + (size_t)(w * 16 + (l & 15)) * 1024 + fko;
    const _Float16* pb = Bt + (size_t)(bx * 64 + (l & 15)) * 1024 + fko;

    f32x4 acc[4];
    const f32x4 fzero = {0.f, 0.f, 0.f, 0.f};
#pragma unroll
    for (int ni = 0; ni < 4; ++ni) acc[ni] = fzero;

#pragma unroll 4
    for (int k0 = 0; k0 < 1024; k0 += 32) {
        half8v a = *(const half8v*)(pa + k0);
#pragma unroll
        for (int ni = 0; ni < 4; ++ni) {
            half8v b = *(const half8v*)(pb + (size_t)ni * 16 * 1024 + k0);
            acc[ni] = __builtin_amdgcn_mfma_f32_16x16x32_f16(a, b, acc[ni], 0, 0, 0);
        }
    }

    const int row0 = w * 16 + (l >> 4) * 4;
    const int col0 = bx * 64 + (l & 15);
#pragma unroll
    for (int ni = 0; ni < 4; ++ni) {
        int col = col0 + ni * 16;
        float bb = bias[col];
#pragma unroll
        for (int r = 0; r < 4; ++r) {
            float v = acc[ni][r] + bb;
            v = v > 0.f ? v : 0.01f * v;
            if (mode == 0) out16[(size_t)(row0 + r) * 1024 + col] = (_Float16)v;
            else out32[(size_t)(row0 + r) * 1024 + col] = v;
        }
    }
}

// ---------------- fc3: one wave per output, f32 shfl reduction ----------------
__global__ void k_fc3(const float* __restrict__ z2, const float* __restrict__ W,
                      const float* __restrict__ b, float* __restrict__ out) {
    int gw = (blockIdx.x * blockDim.x + threadIdx.x) >> 6;
    int lane = threadIdx.x & 63;
    if (gw >= N_GRAPHS * NCLS) return;
    int row = gw / NCLS, col = gw - row * NCLS;
    float s = 0.f;
    for (int k = lane; k < 1024; k += 64) s += z2[(size_t)row * 1024 + k] * W[(size_t)k * NCLS + col];
#pragma unroll
    for (int o = 32; o; o >>= 1) s += __shfl_down(s, o);
    if (lane == 0) out[(size_t)row * NCLS + col] = s + b[col];
}

// ---------------- host orchestration ----------------
extern "C" void kernel_launch(void* const* d_in, const int* in_sizes, int n_in,
                              void* d_out, int out_size, void* d_ws, size_t ws_size,
                              hipStream_t stream) {
    const float* h = (const float*)d_in[0];
    const int* src = (const int*)d_in[1];
    const int* dst = (const int*)d_in[2];
    const int* gid = (const int*)d_in[3];

    const float *w_src[3], *b_src[3], *w_dst[3], *b_dst[3], *attn[3], *bias[3], *gamma[3], *beta[3];
    for (int l = 0; l < 3; ++l) {
        int base = 4 + l * 8;
        w_src[l] = (const float*)d_in[base + 0];
        b_src[l] = (const float*)d_in[base + 1];
        w_dst[l] = (const float*)d_in[base + 2];
        b_dst[l] = (const float*)d_in[base + 3];
        attn[l]  = (const float*)d_in[base + 4];
        bias[l]  = (const float*)d_in[base + 5];
        gamma[l] = (const float*)d_in[base + 6];
        beta[l]  = (const float*)d_in[base + 7];
    }
    const float* fc1_w = (const float*)d_in[28];
    const float* fc1_b = (const float*)d_in[29];
    const float* fc2_w = (const float*)d_in[30];
    const float* fc2_b = (const float*)d_in[31];
    const float* fc3_w = (const float*)d_in[32];
    const float* fc3_b = (const float*)d_in[33];

    // workspace carve
    char* base = (char*)d_ws;
    size_t o = 0;
    auto carve = [&](size_t bytes) -> char* {
        char* p = base + o;
        o += (bytes + 255) & ~(size_t)255;
        return p;
    };
    _Float16* fs16 = (_Float16*)carve((size_t)N_NODES * F * 2);
    _Float16* fd16 = (_Float16*)carve((size_t)N_NODES * F * 2);
    float* y = (float*)carve((size_t)N_NODES * F * 4);
    _Float16* xh = (_Float16*)carve((size_t)N_PAD * F * 2);
    _Float16* wsh = (_Float16*)carve((size_t)F * F * 2);
    _Float16* wdh = (_Float16*)carve((size_t)F * F * 2);
    _Float16* fc1h = (_Float16*)carve((size_t)F * F * 2);
    _Float16* fc2h = (_Float16*)carve((size_t)F * F * 2);
    int* cnt = (int*)carve((size_t)N_NODES * 4);
    int* off = (int*)carve((size_t)(N_NODES + 1) * 4);
    int* cursor = (int*)carve((size_t)N_NODES * 4);
    int* csr_e = (int*)carve((size_t)N_EDGES * 4);
    float* part = (float*)carve((size_t)BN_CHUNKS * 2 * F * 4);
    float* scale = (float*)carve(F * 4);
    float* shift = (float*)carve(F * 4);
    int* gstart = (int*)carve((N_GRAPHS + 1) * 4);
    _Float16* hg16 = (_Float16*)carve((size_t)N_GRAPHS * F * 2);
    _Float16* z1h = (_Float16*)carve((size_t)N_GRAPHS * F * 2);
    float* z2 = (float*)carve((size_t)N_GRAPHS * F * 4);
    (void)ws_size;

    // ---- CSR build (deterministic: buckets sorted by edge id) ----
    k_zero_i32<<<(N_NODES + 255) / 256, 256, 0, stream>>>(cnt, N_NODES);
    k_count<<<(N_EDGES + 255) / 256, 256, 0, stream>>>(dst, cnt);
    k_scan<<<1, 256, 0, stream>>>(cnt, off);
    k_copy_i32<<<(N_NODES + 255) / 256, 256, 0, stream>>>(cursor, off, N_NODES);
    k_fill<<<(N_EDGES + 255) / 256, 256, 0, stream>>>(dst, cursor, csr_e);
    k_sort_buckets<<<(N_NODES + 255) / 256, 256, 0, stream>>>(off, csr_e);
    k_gstart<<<1, 128, 0, stream>>>(gid, gstart);

    // ---- input conversion + pad-row zeroing + MLP weight conversion ----
    k_cvt_h<<<(N_PAD * 64 + 255) / 256, 256, 0, stream>>>(h, xh);
    k_zero_pad<<<((N_PAD - N_NODES) * F + 255) / 256, 256, 0, stream>>>(xh);
    k_cvt_w<<<dim3(F / 32, F / 32), 256, 0, stream>>>(fc1_w, fc1h, F, F);
    k_cvt_w<<<dim3(F / 32, F / 32), 256, 0, stream>>>(fc2_w, fc2h, F, F);

    // ---- 3 GATv2 + BN + lrelu layers ----
    const dim3 ggrid(8, N_PAD / 128);
    for (int l = 0; l < 3; ++l) {
        const int K = (l == 0) ? IN_F : F;
        const int Kp = (l == 0) ? 64 : F;
        k_cvt_w<<<dim3(Kp / 32, F / 32), 256, 0, stream>>>(w_src[l], wsh, K, Kp);
        k_cvt_w<<<dim3(Kp / 32, F / 32), 256, 0, stream>>>(w_dst[l], wdh, K, Kp);
        k_gemm_dual<<<ggrid, 256, 0, stream>>>(xh, wsh, wdh, b_src[l], b_dst[l], fs16, fd16, Kp);
        k_gat<<<N_NODES, 256, 0, stream>>>(fs16, fd16, off, csr_e, src, attn[l], bias[l], y);
        k_bnpart<<<BN_CHUNKS, 256, 0, stream>>>(y, part);
        k_bnfin<<<F / 256, 256, 0, stream>>>(part, gamma[l], beta[l], scale, shift);
        k_bnapply<<<(N_NODES * (F / 4) + 255) / 256, 256, 0, stream>>>(
            y, scale, shift, y, xh, (l == 2) ? 1 : 0);
    }

    // ---- pool + MLP head (MFMA fc1/fc2, wave-reduce fc3) ----
    k_pool<<<dim3(4, N_GRAPHS), 256, 0, stream>>>(y, gstart, hg16);
    k_mlp_mfma<<<16, 256, 0, stream>>>(hg16, fc1h, fc1_b, z1h, nullptr, 0);
    k_mlp_mfma<<<16, 256, 0, stream>>>(z1h, fc2h, fc2_b, nullptr, z2, 1);
    k_fc3<<<(N_GRAPHS * NCLS * 64 + 255) / 256, 256, 0, stream>>>(z2, fc3_w, fc3_b, (float*)d_out);
}